// Round 3
// baseline (447.010 us; speedup 1.0000x reference)
//
#include <hip/hip_runtime.h>
#include <stdint.h>

#define N_NODES 100000
#define N_EDGES 1000000

// ---------- bf16 helpers ----------
static __device__ __forceinline__ float bf2f(unsigned short u) {
    return __uint_as_float(((unsigned int)u) << 16);
}
static __device__ __forceinline__ unsigned short f2bf(float f) {
    unsigned int u = __float_as_uint(f);
    unsigned int r = (u + 0x7FFFu + ((u >> 16) & 1u)) >> 16;  // RNE
    return (unsigned short)r;
}
static __device__ __forceinline__ float4 ld4_half(const unsigned short* p) {
    ushort4 u = *(const ushort4*)p;
    return make_float4(bf2f(u.x), bf2f(u.y), bf2f(u.z), bf2f(u.w));
}
static __device__ __forceinline__ void st4_half(unsigned short* p, float4 f) {
    ushort4 u;
    u.x = f2bf(f.x); u.y = f2bf(f.y); u.z = f2bf(f.z); u.w = f2bf(f.w);
    *(ushort4*)p = u;
}

// ---------- dynamic-dtype external loads (flag: 1 = bf16 memory, 0 = f32) ----------
static __device__ __forceinline__ float ldf(const void* p, size_t i, int bf) {
    return bf ? bf2f(((const unsigned short*)p)[i]) : ((const float*)p)[i];
}
static __device__ __forceinline__ float4 ldf4(const void* p, size_t i, int bf) {
    if (bf) return ld4_half((const unsigned short*)p + i);
    return *(const float4*)((const float*)p + i);
}

// ---------- dtype probe ----------
// Look at the LOW half-word of the first 1024 32-bit words of x.
// f32 data: low halves are mantissa bits -> decoded-as-bf16 exponents are wild.
// bf16 data: low halves are real bf16 values of N(0,1) data -> tame.
__global__ __launch_bounds__(256) void detect_kernel(const unsigned short* __restrict__ xs,
                                                     int* __restrict__ flag) {
    __shared__ int sz;
    if (threadIdx.x == 0) sz = 0;
    __syncthreads();
    int z = 0;
    for (int i = threadIdx.x; i < 1024; i += 256) {
        float av = fabsf(bf2f(xs[2 * i]));
        // wild = NaN/Inf/huge or tiny-but-nonzero
        if (!(av <= 1048576.0f) || (av != 0.0f && av < 9.5367431640625e-07f)) z++;
    }
    atomicAdd(&sz, z);
    __syncthreads();
    if (threadIdx.x == 0) *flag = (sz > 256) ? 0 : 1;
}

// ---------- CSR build: histogram -> scan -> fill -> per-row sort ----------
__global__ __launch_bounds__(256) void hist_kernel(const int* __restrict__ dst,
                                                   int* __restrict__ counts) {
    int e = blockIdx.x * 256 + threadIdx.x;
    if (e < N_EDGES) atomicAdd(&counts[dst[e]], 1);
}

__global__ __launch_bounds__(256) void scan1_kernel(const int* __restrict__ counts,
                                                    int* __restrict__ row_start,
                                                    int* __restrict__ partials) {
    __shared__ int sh[256];
    int tid = threadIdx.x;
    int i0 = blockIdx.x * 1024 + tid * 4;
    int v0 = (i0 + 0 < N_NODES) ? counts[i0 + 0] : 0;
    int v1 = (i0 + 1 < N_NODES) ? counts[i0 + 1] : 0;
    int v2 = (i0 + 2 < N_NODES) ? counts[i0 + 2] : 0;
    int v3 = (i0 + 3 < N_NODES) ? counts[i0 + 3] : 0;
    int tsum = v0 + v1 + v2 + v3;
    sh[tid] = tsum;
    __syncthreads();
    for (int off = 1; off < 256; off <<= 1) {
        int t = 0;
        if (tid >= off) t = sh[tid - off];
        __syncthreads();
        if (tid >= off) sh[tid] += t;
        __syncthreads();
    }
    int excl = sh[tid] - tsum;
    if (i0 + 0 < N_NODES) row_start[i0 + 0] = excl;
    if (i0 + 1 < N_NODES) row_start[i0 + 1] = excl + v0;
    if (i0 + 2 < N_NODES) row_start[i0 + 2] = excl + v0 + v1;
    if (i0 + 3 < N_NODES) row_start[i0 + 3] = excl + v0 + v1 + v2;
    if (tid == 255) partials[blockIdx.x] = sh[255];
}

__global__ __launch_bounds__(128) void scan2_kernel(int* __restrict__ partials, int nchunks) {
    __shared__ int sh[128];
    int tid = threadIdx.x;
    int v = (tid < nchunks) ? partials[tid] : 0;
    sh[tid] = v;
    __syncthreads();
    for (int off = 1; off < 128; off <<= 1) {
        int t = 0;
        if (tid >= off) t = sh[tid - off];
        __syncthreads();
        if (tid >= off) sh[tid] += t;
        __syncthreads();
    }
    if (tid < nchunks) partials[tid] = sh[tid] - v;  // exclusive
}

__global__ __launch_bounds__(256) void scan3_kernel(const int* __restrict__ partials,
                                                    int* __restrict__ row_start,
                                                    int* __restrict__ cursor) {
    int i = blockIdx.x * 256 + threadIdx.x;
    if (i < N_NODES) {
        int v = row_start[i] + partials[i >> 10];
        row_start[i] = v;
        cursor[i] = v;
    }
    if (i == 0) row_start[N_NODES] = N_EDGES;
}

__global__ __launch_bounds__(256) void fill_kernel(const int* __restrict__ src,
                                                   const int* __restrict__ dst,
                                                   const void* __restrict__ val,
                                                   int* __restrict__ cursor,
                                                   int* __restrict__ csr_src,
                                                   float* __restrict__ csr_val,
                                                   int* __restrict__ csr_eid,
                                                   const int* __restrict__ flagp) {
    int bf = *flagp;
    int e = blockIdx.x * 256 + threadIdx.x;
    if (e < N_EDGES) {
        int d = dst[e];
        int pos = atomicAdd(&cursor[d], 1);
        csr_src[pos] = src[e];
        csr_val[pos] = ldf(val, e, bf);
        csr_eid[pos] = e;
    }
}

// Deterministic CSR: sort each row's entries by original edge id (matches
// segment_sum accumulation order and makes output a pure function of inputs).
__global__ __launch_bounds__(256) void sortrow_kernel(const int* __restrict__ row_start,
                                                      int* __restrict__ eid,
                                                      int* __restrict__ src,
                                                      float* __restrict__ val) {
    int r = blockIdx.x * 256 + threadIdx.x;
    if (r >= N_NODES) return;
    int s = row_start[r], e = row_start[r + 1];
    for (int i = s + 1; i < e; ++i) {
        int ke = eid[i]; int ks = src[i]; float kv = val[i];
        int j = i - 1;
        while (j >= s && eid[j] > ke) {
            eid[j + 1] = eid[j]; src[j + 1] = src[j]; val[j + 1] = val[j];
            --j;
        }
        eid[j + 1] = ke; src[j + 1] = ks; val[j + 1] = kv;
    }
}

// ---------- dense GEMM: out[N x M] = h[N x K] @ W[K x M], f32 accumulate ----------
// DYNIN: h is an external input (dtype per flag). HALF: internal buffers are bf16.
template <int K, int M, bool DYNIN, bool HALF>
__global__ __launch_bounds__(256) void gemm_kernel(const void* __restrict__ hv_,
                                                   const void* __restrict__ W,
                                                   void* __restrict__ out_,
                                                   const int* __restrict__ flagp) {
    constexpr int TILE = (K == 128) ? 32 : 64;
    constexpr int CT = M / 4;
    constexpr int ROWT = 256 / CT;
    constexpr int RT = TILE / ROWT;
    constexpr int HS = K + 4;

    __shared__ float hs[TILE][HS];
    __shared__ float ws[K][M];

    const int bf = *flagp;
    const int tid = threadIdx.x;
    const int base = blockIdx.x * TILE;

    for (int i = tid * 4; i < K * M; i += 1024) {
        *(float4*)(&ws[0][0] + i) = ldf4(W, i, bf);
    }
    for (int i = tid * 4; i < TILE * K; i += 1024) {
        int r = i / K;
        int kk = i & (K - 1);
        int grow = base + r;
        float4 f = make_float4(0.f, 0.f, 0.f, 0.f);
        if (grow < N_NODES) {
            if (DYNIN) {
                f = ldf4(hv_, (size_t)grow * K + kk, bf);
            } else if (HALF) {
                f = ld4_half((const unsigned short*)hv_ + (size_t)grow * K + kk);
            } else {
                f = *(const float4*)((const float*)hv_ + (size_t)grow * K + kk);
            }
        }
        *(float4*)(&hs[r][kk]) = f;
    }
    __syncthreads();

    const int tx = tid % CT, ty = tid / CT;
    const int c0 = tx * 4, r0 = ty * RT;

    float acc[RT][4];
#pragma unroll
    for (int i = 0; i < RT; ++i) {
        acc[i][0] = 0.f; acc[i][1] = 0.f; acc[i][2] = 0.f; acc[i][3] = 0.f;
    }

#pragma unroll 4
    for (int k = 0; k < K; k += 4) {
        float4 w0 = *(const float4*)&ws[k + 0][c0];
        float4 w1 = *(const float4*)&ws[k + 1][c0];
        float4 w2 = *(const float4*)&ws[k + 2][c0];
        float4 w3 = *(const float4*)&ws[k + 3][c0];
#pragma unroll
        for (int i = 0; i < RT; ++i) {
            float4 h4 = *(const float4*)&hs[r0 + i][k];
            acc[i][0] += h4.x * w0.x + h4.y * w1.x + h4.z * w2.x + h4.w * w3.x;
            acc[i][1] += h4.x * w0.y + h4.y * w1.y + h4.z * w2.y + h4.w * w3.y;
            acc[i][2] += h4.x * w0.z + h4.y * w1.z + h4.z * w2.z + h4.w * w3.z;
            acc[i][3] += h4.x * w0.w + h4.y * w1.w + h4.z * w2.w + h4.w * w3.w;
        }
    }

#pragma unroll
    for (int i = 0; i < RT; ++i) {
        int row = base + r0 + i;
        if (row < N_NODES) {
            float4 f = make_float4(acc[i][0], acc[i][1], acc[i][2], acc[i][3]);
            if (HALF) st4_half((unsigned short*)out_ + (size_t)row * M + c0, f);
            else      *(float4*)((float*)out_ + (size_t)row * M + c0) = f;
        }
    }
}

// ---------- SpMM (gather, no atomics): out[d] = act(bias + sum_e val*support[src]) ----------
// DYNOUT: final layer writes external dtype (per flag). HALF: internal buffers bf16.
template <int M, bool RELU, bool DYNOUT, bool HALF>
__global__ __launch_bounds__(256) void spmm_kernel(const void* __restrict__ support_,
                                                   const int* __restrict__ row_start,
                                                   const int* __restrict__ csr_src,
                                                   const float* __restrict__ csr_val,
                                                   const void* __restrict__ bias,
                                                   void* __restrict__ out_,
                                                   const int* __restrict__ flagp) {
    constexpr int GROUP = M / 4;
    constexpr int GPB = 256 / GROUP;
    int bf = *flagp;
    int tid = threadIdx.x;
    int gid = blockIdx.x * GPB + tid / GROUP;
    int c0 = (tid % GROUP) * 4;
    if (gid >= N_NODES) return;
    int s = row_start[gid];
    int e = row_start[gid + 1];
    float a0 = ldf(bias, c0 + 0, bf);
    float a1 = ldf(bias, c0 + 1, bf);
    float a2 = ldf(bias, c0 + 2, bf);
    float a3 = ldf(bias, c0 + 3, bf);
    for (int j = s; j < e; ++j) {
        int src = csr_src[j];
        float v = csr_val[j];
        float4 sp;
        if (HALF) sp = ld4_half((const unsigned short*)support_ + (size_t)src * M + c0);
        else      sp = *(const float4*)((const float*)support_ + (size_t)src * M + c0);
        a0 += v * sp.x; a1 += v * sp.y; a2 += v * sp.z; a3 += v * sp.w;
    }
    if (RELU) {
        a0 = fmaxf(a0, 0.f); a1 = fmaxf(a1, 0.f);
        a2 = fmaxf(a2, 0.f); a3 = fmaxf(a3, 0.f);
    }
    float4 f = make_float4(a0, a1, a2, a3);
    if (DYNOUT) {
        if (bf) st4_half((unsigned short*)out_ + (size_t)gid * M + c0, f);
        else    *(float4*)((float*)out_ + (size_t)gid * M + c0) = f;
    } else if (HALF) {
        st4_half((unsigned short*)out_ + (size_t)gid * M + c0, f);
    } else {
        *(float4*)((float*)out_ + (size_t)gid * M + c0) = f;
    }
}

extern "C" void kernel_launch(void* const* d_in, const int* in_sizes, int n_in,
                              void* d_out, int out_size, void* d_ws, size_t ws_size,
                              hipStream_t stream) {
    (void)in_sizes; (void)n_in; (void)out_size;
    const void* x  = d_in[0];
    const void* ev = d_in[1];
    const void* W1 = d_in[2];
    const void* b1 = d_in[3];
    const void* W2 = d_in[4];
    const void* b2 = d_in[5];
    const void* W3 = d_in[6];
    const void* b3 = d_in[7];
    const int* esrc = (const int*)d_in[8];
    const int* edst = (const int*)d_in[9];

    // ---- workspace budgeting (NEVER exceed ws_size) ----
    // full (f32 intermediates): 2*25.6MB + 12MB csr + ~1.3MB misc ~= 64.5MB
    // compact (bf16 intermediates): 2*12.8MB + 12MB csr + ~1.3MB ~= 39MB
    const size_t full_need = (size_t)N_NODES * 64 * 4 * 2 + (size_t)N_EDGES * 4 * 3 +
                             (size_t)(3 * N_NODES + 1) * 4 + 16384;
    const bool full = (ws_size == 0) || (ws_size >= full_need);

    char* ws = (char*)d_ws;
    size_t off = 0;
    auto alloc = [&](size_t bytes) -> void* {
        void* p = ws + off;
        off = (off + bytes + 255) & ~(size_t)255;
        return p;
    };
    const size_t ab_es = full ? 4 : 2;  // element size of intermediates
    void* A         = alloc((size_t)N_NODES * 64 * ab_es);
    void* B         = alloc((size_t)N_NODES * 64 * ab_es);
    int* counts     = (int*)alloc((size_t)N_NODES * 4);
    int* row_start  = (int*)alloc((size_t)(N_NODES + 1) * 4);
    int* cursor     = (int*)alloc((size_t)N_NODES * 4);
    int* partials   = (int*)alloc(512);
    int* csr_src    = (int*)alloc((size_t)N_EDGES * 4);
    float* csr_val  = (float*)alloc((size_t)N_EDGES * 4);
    int* csr_eid    = (int*)alloc((size_t)N_EDGES * 4);
    int* flagp      = (int*)alloc(256);

    // ---- dtype probe ----
    detect_kernel<<<1, 256, 0, stream>>>((const unsigned short*)x, flagp);

    // ---- deterministic CSR build (by dst) ----
    hipMemsetAsync(counts, 0, (size_t)N_NODES * 4, stream);
    int eb = (N_EDGES + 255) / 256;
    hist_kernel<<<eb, 256, 0, stream>>>(edst, counts);
    int nchunks = (N_NODES + 1023) / 1024;  // 98
    scan1_kernel<<<nchunks, 256, 0, stream>>>(counts, row_start, partials);
    scan2_kernel<<<1, 128, 0, stream>>>(partials, nchunks);
    scan3_kernel<<<(N_NODES + 255) / 256, 256, 0, stream>>>(partials, row_start, cursor);
    fill_kernel<<<eb, 256, 0, stream>>>(esrc, edst, ev, cursor, csr_src, csr_val, csr_eid, flagp);
    sortrow_kernel<<<(N_NODES + 255) / 256, 256, 0, stream>>>(row_start, csr_eid, csr_src, csr_val);

    int g128 = (N_NODES + 31) / 32;
    int g64  = (N_NODES + 63) / 64;
    int gs64 = (N_NODES + 15) / 16;

    if (full) {
        gemm_kernel<128, 64, true,  false><<<g128, 256, 0, stream>>>(x, W1, A, flagp);
        spmm_kernel<64, true,  false, false><<<gs64, 256, 0, stream>>>(A, row_start, csr_src, csr_val, b1, B, flagp);
        gemm_kernel<64, 64, false, false><<<g64, 256, 0, stream>>>(B, W2, A, flagp);
        spmm_kernel<64, true,  false, false><<<gs64, 256, 0, stream>>>(A, row_start, csr_src, csr_val, b2, B, flagp);
        gemm_kernel<64, 16, false, false><<<g64, 256, 0, stream>>>(B, W3, A, flagp);
        spmm_kernel<16, false, true,  false><<<g64, 256, 0, stream>>>(A, row_start, csr_src, csr_val, b3, d_out, flagp);
    } else {
        gemm_kernel<128, 64, true,  true><<<g128, 256, 0, stream>>>(x, W1, A, flagp);
        spmm_kernel<64, true,  false, true><<<gs64, 256, 0, stream>>>(A, row_start, csr_src, csr_val, b1, B, flagp);
        gemm_kernel<64, 64, false, true><<<g64, 256, 0, stream>>>(B, W2, A, flagp);
        spmm_kernel<64, true,  false, true><<<gs64, 256, 0, stream>>>(A, row_start, csr_src, csr_val, b2, B, flagp);
        gemm_kernel<64, 16, false, true><<<g64, 256, 0, stream>>>(B, W3, A, flagp);
        spmm_kernel<16, false, true,  true><<<g64, 256, 0, stream>>>(A, row_start, csr_src, csr_val, b3, d_out, flagp);
    }
}

// Round 4
// 395.628 us; speedup vs baseline: 1.1299x; 1.1299x over previous
//
#include <hip/hip_runtime.h>
#include <stdint.h>

#define N_NODES 100000
#define N_EDGES 1000000

// ---------- bf16 helpers ----------
static __device__ __forceinline__ float bf2f(unsigned short u) {
    return __uint_as_float(((unsigned int)u) << 16);
}
static __device__ __forceinline__ unsigned short f2bf(float f) {
    unsigned int u = __float_as_uint(f);
    unsigned int r = (u + 0x7FFFu + ((u >> 16) & 1u)) >> 16;  // RNE
    return (unsigned short)r;
}
static __device__ __forceinline__ float4 ld4_half(const unsigned short* p) {
    ushort4 u = *(const ushort4*)p;
    return make_float4(bf2f(u.x), bf2f(u.y), bf2f(u.z), bf2f(u.w));
}
static __device__ __forceinline__ void st4_half(unsigned short* p, float4 f) {
    ushort4 u;
    u.x = f2bf(f.x); u.y = f2bf(f.y); u.z = f2bf(f.z); u.w = f2bf(f.w);
    *(ushort4*)p = u;
}

// ---------- dynamic-dtype external loads (flag: 1 = bf16 memory, 0 = f32) ----------
static __device__ __forceinline__ float ldf(const void* p, size_t i, int bf) {
    return bf ? bf2f(((const unsigned short*)p)[i]) : ((const float*)p)[i];
}
static __device__ __forceinline__ float4 ldf4(const void* p, size_t i, int bf) {
    if (bf) return ld4_half((const unsigned short*)p + i);
    return *(const float4*)((const float*)p + i);
}

// ---------- dtype probe (low half-words of f32 data decode as wild bf16) ----------
__global__ __launch_bounds__(256) void detect_kernel(const unsigned short* __restrict__ xs,
                                                     int* __restrict__ flag) {
    __shared__ int sz;
    if (threadIdx.x == 0) sz = 0;
    __syncthreads();
    int z = 0;
    for (int i = threadIdx.x; i < 1024; i += 256) {
        float av = fabsf(bf2f(xs[2 * i]));
        if (!(av <= 1048576.0f) || (av != 0.0f && av < 9.5367431640625e-07f)) z++;
    }
    atomicAdd(&sz, z);
    __syncthreads();
    if (threadIdx.x == 0) *flag = (sz > 256) ? 0 : 1;
}

// ---------- CSR build: histogram -> scan -> fill (AoS 8B records) ----------
__global__ __launch_bounds__(256) void hist_kernel(const int* __restrict__ dst,
                                                   int* __restrict__ counts) {
    int e = blockIdx.x * 256 + threadIdx.x;
    if (e < N_EDGES) atomicAdd(&counts[dst[e]], 1);
}

__global__ __launch_bounds__(256) void scan1_kernel(const int* __restrict__ counts,
                                                    int* __restrict__ row_start,
                                                    int* __restrict__ partials) {
    __shared__ int sh[256];
    int tid = threadIdx.x;
    int i0 = blockIdx.x * 1024 + tid * 4;
    int v0 = (i0 + 0 < N_NODES) ? counts[i0 + 0] : 0;
    int v1 = (i0 + 1 < N_NODES) ? counts[i0 + 1] : 0;
    int v2 = (i0 + 2 < N_NODES) ? counts[i0 + 2] : 0;
    int v3 = (i0 + 3 < N_NODES) ? counts[i0 + 3] : 0;
    int tsum = v0 + v1 + v2 + v3;
    sh[tid] = tsum;
    __syncthreads();
    for (int off = 1; off < 256; off <<= 1) {
        int t = 0;
        if (tid >= off) t = sh[tid - off];
        __syncthreads();
        if (tid >= off) sh[tid] += t;
        __syncthreads();
    }
    int excl = sh[tid] - tsum;
    if (i0 + 0 < N_NODES) row_start[i0 + 0] = excl;
    if (i0 + 1 < N_NODES) row_start[i0 + 1] = excl + v0;
    if (i0 + 2 < N_NODES) row_start[i0 + 2] = excl + v0 + v1;
    if (i0 + 3 < N_NODES) row_start[i0 + 3] = excl + v0 + v1 + v2;
    if (tid == 255) partials[blockIdx.x] = sh[255];
}

__global__ __launch_bounds__(128) void scan2_kernel(int* __restrict__ partials, int nchunks) {
    __shared__ int sh[128];
    int tid = threadIdx.x;
    int v = (tid < nchunks) ? partials[tid] : 0;
    sh[tid] = v;
    __syncthreads();
    for (int off = 1; off < 128; off <<= 1) {
        int t = 0;
        if (tid >= off) t = sh[tid - off];
        __syncthreads();
        if (tid >= off) sh[tid] += t;
        __syncthreads();
    }
    if (tid < nchunks) partials[tid] = sh[tid] - v;  // exclusive
}

__global__ __launch_bounds__(256) void scan3_kernel(const int* __restrict__ partials,
                                                    int* __restrict__ row_start,
                                                    int* __restrict__ cursor) {
    int i = blockIdx.x * 256 + threadIdx.x;
    if (i < N_NODES) {
        int v = row_start[i] + partials[i >> 10];
        row_start[i] = v;
        cursor[i] = v;
    }
    if (i == 0) row_start[N_NODES] = N_EDGES;
}

// one 8B AoS record per edge: {src, val_bits}
__global__ __launch_bounds__(256) void fill_kernel(const int* __restrict__ src,
                                                   const int* __restrict__ dst,
                                                   const void* __restrict__ val,
                                                   int* __restrict__ cursor,
                                                   int2* __restrict__ csr_rec,
                                                   const int* __restrict__ flagp) {
    int bf = *flagp;
    int e = blockIdx.x * 256 + threadIdx.x;
    if (e < N_EDGES) {
        int d = dst[e];
        int pos = atomicAdd(&cursor[d], 1);
        int2 rec;
        rec.x = src[e];
        rec.y = __float_as_int(ldf(val, e, bf));
        csr_rec[pos] = rec;
    }
}

// ---------- dense GEMM: out[N x M] = h[N x K] @ W[K x M], f32 acc, bf16 out ----------
// DYNIN: h is an external input (dtype per flag); else internal bf16.
template <int K, int M, bool DYNIN>
__global__ __launch_bounds__(256) void gemm_kernel(const void* __restrict__ hv_,
                                                   const void* __restrict__ W,
                                                   unsigned short* __restrict__ out,
                                                   const int* __restrict__ flagp) {
    constexpr int TILE = (K == 128) ? 32 : 64;
    constexpr int CT = M / 4;
    constexpr int ROWT = 256 / CT;
    constexpr int RT = TILE / ROWT;
    constexpr int HS = K + 4;

    __shared__ float hs[TILE][HS];
    __shared__ float ws[K][M];

    const int bf = *flagp;
    const int tid = threadIdx.x;
    const int base = blockIdx.x * TILE;

    for (int i = tid * 4; i < K * M; i += 1024) {
        *(float4*)(&ws[0][0] + i) = ldf4(W, i, bf);
    }
    for (int i = tid * 4; i < TILE * K; i += 1024) {
        int r = i / K;
        int kk = i & (K - 1);
        int grow = base + r;
        float4 f = make_float4(0.f, 0.f, 0.f, 0.f);
        if (grow < N_NODES) {
            if (DYNIN) f = ldf4(hv_, (size_t)grow * K + kk, bf);
            else       f = ld4_half((const unsigned short*)hv_ + (size_t)grow * K + kk);
        }
        *(float4*)(&hs[r][kk]) = f;
    }
    __syncthreads();

    const int tx = tid % CT, ty = tid / CT;
    const int c0 = tx * 4, r0 = ty * RT;

    float acc[RT][4];
#pragma unroll
    for (int i = 0; i < RT; ++i) {
        acc[i][0] = 0.f; acc[i][1] = 0.f; acc[i][2] = 0.f; acc[i][3] = 0.f;
    }

#pragma unroll 4
    for (int k = 0; k < K; k += 4) {
        float4 w0 = *(const float4*)&ws[k + 0][c0];
        float4 w1 = *(const float4*)&ws[k + 1][c0];
        float4 w2 = *(const float4*)&ws[k + 2][c0];
        float4 w3 = *(const float4*)&ws[k + 3][c0];
#pragma unroll
        for (int i = 0; i < RT; ++i) {
            float4 h4 = *(const float4*)&hs[r0 + i][k];
            acc[i][0] += h4.x * w0.x + h4.y * w1.x + h4.z * w2.x + h4.w * w3.x;
            acc[i][1] += h4.x * w0.y + h4.y * w1.y + h4.z * w2.y + h4.w * w3.y;
            acc[i][2] += h4.x * w0.z + h4.y * w1.z + h4.z * w2.z + h4.w * w3.z;
            acc[i][3] += h4.x * w0.w + h4.y * w1.w + h4.z * w2.w + h4.w * w3.w;
        }
    }

#pragma unroll
    for (int i = 0; i < RT; ++i) {
        int row = base + r0 + i;
        if (row < N_NODES) {
            float4 f = make_float4(acc[i][0], acc[i][1], acc[i][2], acc[i][3]);
            st4_half(out + (size_t)row * M + c0, f);
        }
    }
}

// ---------- SpMM (gather, no atomics): out[d] = act(bias + sum_e val*support[src]) ----------
// support is internal bf16. DYNOUT: final layer writes external dtype per flag.
template <int M, bool RELU, bool DYNOUT>
__global__ __launch_bounds__(256) void spmm_kernel(const unsigned short* __restrict__ support,
                                                   const int* __restrict__ row_start,
                                                   const int2* __restrict__ csr_rec,
                                                   const void* __restrict__ bias,
                                                   void* __restrict__ out_,
                                                   const int* __restrict__ flagp) {
    constexpr int GROUP = M / 4;
    constexpr int GPB = 256 / GROUP;
    int bf = *flagp;
    int tid = threadIdx.x;
    int gid = blockIdx.x * GPB + tid / GROUP;
    int c0 = (tid % GROUP) * 4;
    if (gid >= N_NODES) return;
    int s = row_start[gid];
    int e = row_start[gid + 1];
    float a0 = ldf(bias, c0 + 0, bf);
    float a1 = ldf(bias, c0 + 1, bf);
    float a2 = ldf(bias, c0 + 2, bf);
    float a3 = ldf(bias, c0 + 3, bf);
    for (int j = s; j < e; ++j) {
        int2 rec = csr_rec[j];
        float v = __int_as_float(rec.y);
        float4 sp = ld4_half(support + (size_t)rec.x * M + c0);
        a0 += v * sp.x; a1 += v * sp.y; a2 += v * sp.z; a3 += v * sp.w;
    }
    if (RELU) {
        a0 = fmaxf(a0, 0.f); a1 = fmaxf(a1, 0.f);
        a2 = fmaxf(a2, 0.f); a3 = fmaxf(a3, 0.f);
    }
    float4 f = make_float4(a0, a1, a2, a3);
    if (DYNOUT) {
        if (bf) st4_half((unsigned short*)out_ + (size_t)gid * M + c0, f);
        else    *(float4*)((float*)out_ + (size_t)gid * M + c0) = f;
    } else {
        st4_half((unsigned short*)out_ + (size_t)gid * M + c0, f);
    }
}

extern "C" void kernel_launch(void* const* d_in, const int* in_sizes, int n_in,
                              void* d_out, int out_size, void* d_ws, size_t ws_size,
                              hipStream_t stream) {
    (void)in_sizes; (void)n_in; (void)out_size; (void)ws_size;
    const void* x  = d_in[0];
    const void* ev = d_in[1];
    const void* W1 = d_in[2];
    const void* b1 = d_in[3];
    const void* W2 = d_in[4];
    const void* b2 = d_in[5];
    const void* W3 = d_in[6];
    const void* b3 = d_in[7];
    const int* esrc = (const int*)d_in[8];
    const int* edst = (const int*)d_in[9];

    // workspace (~35 MB; fits the observed budget with margin)
    char* ws = (char*)d_ws;
    size_t off = 0;
    auto alloc = [&](size_t bytes) -> void* {
        void* p = ws + off;
        off = (off + bytes + 255) & ~(size_t)255;
        return p;
    };
    unsigned short* A = (unsigned short*)alloc((size_t)N_NODES * 64 * 2);  // support (bf16)
    unsigned short* B = (unsigned short*)alloc((size_t)N_NODES * 64 * 2);  // agg (bf16)
    int* counts     = (int*)alloc((size_t)N_NODES * 4);
    int* row_start  = (int*)alloc((size_t)(N_NODES + 1) * 4);
    int* cursor     = (int*)alloc((size_t)N_NODES * 4);
    int* partials   = (int*)alloc(512);
    int2* csr_rec   = (int2*)alloc((size_t)N_EDGES * 8);
    int* flagp      = (int*)alloc(256);

    // ---- dtype probe ----
    detect_kernel<<<1, 256, 0, stream>>>((const unsigned short*)x, flagp);

    // ---- CSR build (by dst) ----
    hipMemsetAsync(counts, 0, (size_t)N_NODES * 4, stream);
    int eb = (N_EDGES + 255) / 256;
    hist_kernel<<<eb, 256, 0, stream>>>(edst, counts);
    int nchunks = (N_NODES + 1023) / 1024;  // 98
    scan1_kernel<<<nchunks, 256, 0, stream>>>(counts, row_start, partials);
    scan2_kernel<<<1, 128, 0, stream>>>(partials, nchunks);
    scan3_kernel<<<(N_NODES + 255) / 256, 256, 0, stream>>>(partials, row_start, cursor);
    fill_kernel<<<eb, 256, 0, stream>>>(esrc, edst, ev, cursor, csr_rec, flagp);

    int g128 = (N_NODES + 31) / 32;
    int g64  = (N_NODES + 63) / 64;
    int gs64 = (N_NODES + 15) / 16;

    // ---- layer 1 ----
    gemm_kernel<128, 64, true><<<g128, 256, 0, stream>>>(x, W1, A, flagp);
    spmm_kernel<64, true, false><<<gs64, 256, 0, stream>>>(A, row_start, csr_rec, b1, B, flagp);
    // ---- layer 2 ----
    gemm_kernel<64, 64, false><<<g64, 256, 0, stream>>>(B, W2, A, flagp);
    spmm_kernel<64, true, false><<<gs64, 256, 0, stream>>>(A, row_start, csr_rec, b2, B, flagp);
    // ---- layer 3 ----
    gemm_kernel<64, 16, false><<<g64, 256, 0, stream>>>(B, W3, A, flagp);
    spmm_kernel<16, false, true><<<g64, 256, 0, stream>>>(A, row_start, csr_rec, b3, d_out, flagp);
}

// Round 5
// 326.153 us; speedup vs baseline: 1.3706x; 1.2130x over previous
//
#include <hip/hip_runtime.h>
#include <stdint.h>

#define N_NODES 100000
#define N_EDGES 1000000
#define NBUCK 98  // ceil(N_NODES / 1024)

// ---------- bf16 helpers ----------
static __device__ __forceinline__ float bf2f(unsigned short u) {
    return __uint_as_float(((unsigned int)u) << 16);
}
static __device__ __forceinline__ unsigned short f2bf(float f) {
    unsigned int u = __float_as_uint(f);
    unsigned int r = (u + 0x7FFFu + ((u >> 16) & 1u)) >> 16;  // RNE
    return (unsigned short)r;
}
static __device__ __forceinline__ float4 ld4_half(const unsigned short* p) {
    ushort4 u = *(const ushort4*)p;
    return make_float4(bf2f(u.x), bf2f(u.y), bf2f(u.z), bf2f(u.w));
}
static __device__ __forceinline__ void st4_half(unsigned short* p, float4 f) {
    ushort4 u;
    u.x = f2bf(f.x); u.y = f2bf(f.y); u.z = f2bf(f.z); u.w = f2bf(f.w);
    *(ushort4*)p = u;
}

// ---------- dynamic-dtype external loads (flag: 1 = bf16 memory, 0 = f32) ----------
static __device__ __forceinline__ float ldf(const void* p, size_t i, int bf) {
    return bf ? bf2f(((const unsigned short*)p)[i]) : ((const float*)p)[i];
}
static __device__ __forceinline__ float4 ldf4(const void* p, size_t i, int bf) {
    if (bf) return ld4_half((const unsigned short*)p + i);
    return *(const float4*)((const float*)p + i);
}

// ---------- dtype probe (low half-words of f32 data decode as wild bf16) ----------
__global__ __launch_bounds__(256) void detect_kernel(const unsigned short* __restrict__ xs,
                                                     int* __restrict__ flag) {
    __shared__ int sz;
    if (threadIdx.x == 0) sz = 0;
    __syncthreads();
    int z = 0;
    for (int i = threadIdx.x; i < 1024; i += 256) {
        float av = fabsf(bf2f(xs[2 * i]));
        if (!(av <= 1048576.0f) || (av != 0.0f && av < 9.5367431640625e-07f)) z++;
    }
    atomicAdd(&sz, z);
    __syncthreads();
    if (threadIdx.x == 0) *flag = (sz > 256) ? 0 : 1;
}

// ---------- CSR build, bucket-local (no random global scatter) ----------
// Bucket = 1024 consecutive dst rows. 98 buckets.

// 1) bucket histogram, LDS-staged
__global__ __launch_bounds__(256) void bhist_kernel(const int* __restrict__ dst,
                                                    int* __restrict__ bcount) {
    __shared__ int cnt[NBUCK];
    int tid = threadIdx.x;
    for (int i = tid; i < NBUCK; i += 256) cnt[i] = 0;
    __syncthreads();
    int e0 = blockIdx.x * 4096;
#pragma unroll
    for (int i = 0; i < 16; ++i) {
        int e = e0 + i * 256 + tid;
        if (e < N_EDGES) atomicAdd(&cnt[dst[e] >> 10], 1);
    }
    __syncthreads();
    for (int i = tid; i < NBUCK; i += 256) {
        int c = cnt[i];
        if (c) atomicAdd(&bcount[i], c);
    }
}

// 2) scan 98 bucket counts -> bucket regions + cursors
__global__ __launch_bounds__(128) void bscan_kernel(const int* __restrict__ bcount,
                                                    int* __restrict__ bstart,
                                                    int* __restrict__ bcursor) {
    __shared__ int sh[128];
    int tid = threadIdx.x;
    int v = (tid < NBUCK) ? bcount[tid] : 0;
    sh[tid] = v;
    __syncthreads();
    for (int off = 1; off < 128; off <<= 1) {
        int t = 0;
        if (tid >= off) t = sh[tid - off];
        __syncthreads();
        if (tid >= off) sh[tid] += t;
        __syncthreads();
    }
    if (tid < NBUCK) {
        int excl = sh[tid] - v;
        bstart[tid] = excl;
        bcursor[tid] = excl;
    }
    if (tid == NBUCK - 1) bstart[NBUCK] = sh[tid];
}

// 3) partition edges into bucket regions. rec = {src | dst_local<<17, val_bits}
__global__ __launch_bounds__(256) void part_kernel(const int* __restrict__ src,
                                                   const int* __restrict__ dst,
                                                   const void* __restrict__ val,
                                                   int* __restrict__ bcursor,
                                                   int2* __restrict__ part,
                                                   const int* __restrict__ flagp) {
    __shared__ int cnt[NBUCK];
    __shared__ int base[NBUCK];
    const int bf = *flagp;
    const int tid = threadIdx.x;
    const int e0 = blockIdx.x * 2048;
    for (int i = tid; i < NBUCK; i += 256) cnt[i] = 0;
    __syncthreads();
    int rank[8], bkt[8], pk[8], vb[8];
#pragma unroll
    for (int i = 0; i < 8; ++i) {
        int e = e0 + i * 256 + tid;
        bkt[i] = -1;
        if (e < N_EDGES) {
            int d = dst[e];
            int b = d >> 10;
            bkt[i] = b;
            pk[i] = src[e] | ((d & 1023) << 17);
            vb[i] = __float_as_int(ldf(val, e, bf));
            rank[i] = atomicAdd(&cnt[b], 1);
        }
    }
    __syncthreads();
    for (int i = tid; i < NBUCK; i += 256) {
        int c = cnt[i];
        base[i] = c ? atomicAdd(&bcursor[i], c) : 0;
    }
    __syncthreads();
#pragma unroll
    for (int i = 0; i < 8; ++i) {
        if (bkt[i] >= 0) part[(size_t)base[bkt[i]] + rank[i]] = make_int2(pk[i], vb[i]);
    }
}

// 4) exact placement within each bucket: LDS row-histogram + scan + LDS cursors.
//    Also produces row_start[]. All global writes confined to this bucket's region.
__global__ __launch_bounds__(512) void place_kernel(const int* __restrict__ bstart,
                                                    const int2* __restrict__ part,
                                                    int* __restrict__ row_start,
                                                    int2* __restrict__ csr_rec) {
    __shared__ int cnt[1024];
    __shared__ int sums[512];
    const int tid = threadIdx.x;
    const int b = blockIdx.x;
    const int row0 = b << 10;
    const int nrows = min(1024, N_NODES - row0);
    const int s = bstart[b], e = bstart[b + 1];

    for (int i = tid; i < 1024; i += 512) cnt[i] = 0;
    __syncthreads();
    for (int j = s + tid; j < e; j += 512) {
        unsigned p = (unsigned)part[j].x;
        atomicAdd(&cnt[p >> 17], 1);
    }
    __syncthreads();
    // scan 1024 counts (2 per thread)
    int a0 = cnt[2 * tid], a1 = cnt[2 * tid + 1];
    int ts = a0 + a1;
    sums[tid] = ts;
    __syncthreads();
    for (int off = 1; off < 512; off <<= 1) {
        int t = 0;
        if (tid >= off) t = sums[tid - off];
        __syncthreads();
        if (tid >= off) sums[tid] += t;
        __syncthreads();
    }
    int excl = sums[tid] - ts;
    cnt[2 * tid] = s + excl;          // becomes running cursor
    cnt[2 * tid + 1] = s + excl + a0;
    if (2 * tid < nrows)     row_start[row0 + 2 * tid] = s + excl;
    if (2 * tid + 1 < nrows) row_start[row0 + 2 * tid + 1] = s + excl + a0;
    if (b == NBUCK - 1 && tid == 0) row_start[N_NODES] = e;
    __syncthreads();
    // place: writes land within [s,e) — an ~80KB window
    for (int j = s + tid; j < e; j += 512) {
        int2 r = part[j];
        unsigned p = (unsigned)r.x;
        int pos = atomicAdd(&cnt[p >> 17], 1);
        csr_rec[pos] = make_int2((int)(p & 0x1FFFFu), r.y);
    }
}

// ---------- dense GEMM: out[N x M] = h[N x K] @ W[K x M], f32 acc, bf16 out ----------
template <int K, int M, bool DYNIN>
__global__ __launch_bounds__(256) void gemm_kernel(const void* __restrict__ hv_,
                                                   const void* __restrict__ W,
                                                   unsigned short* __restrict__ out,
                                                   const int* __restrict__ flagp) {
    constexpr int TILE = (K == 128) ? 32 : 64;
    constexpr int CT = M / 4;
    constexpr int ROWT = 256 / CT;
    constexpr int RT = TILE / ROWT;
    constexpr int HS = K + 4;

    __shared__ float hs[TILE][HS];
    __shared__ float ws[K][M];

    const int bf = *flagp;
    const int tid = threadIdx.x;
    const int base = blockIdx.x * TILE;

    for (int i = tid * 4; i < K * M; i += 1024) {
        *(float4*)(&ws[0][0] + i) = ldf4(W, i, bf);
    }
    for (int i = tid * 4; i < TILE * K; i += 1024) {
        int r = i / K;
        int kk = i & (K - 1);
        int grow = base + r;
        float4 f = make_float4(0.f, 0.f, 0.f, 0.f);
        if (grow < N_NODES) {
            if (DYNIN) f = ldf4(hv_, (size_t)grow * K + kk, bf);
            else       f = ld4_half((const unsigned short*)hv_ + (size_t)grow * K + kk);
        }
        *(float4*)(&hs[r][kk]) = f;
    }
    __syncthreads();

    const int tx = tid % CT, ty = tid / CT;
    const int c0 = tx * 4, r0 = ty * RT;

    float acc[RT][4];
#pragma unroll
    for (int i = 0; i < RT; ++i) {
        acc[i][0] = 0.f; acc[i][1] = 0.f; acc[i][2] = 0.f; acc[i][3] = 0.f;
    }

#pragma unroll 4
    for (int k = 0; k < K; k += 4) {
        float4 w0 = *(const float4*)&ws[k + 0][c0];
        float4 w1 = *(const float4*)&ws[k + 1][c0];
        float4 w2 = *(const float4*)&ws[k + 2][c0];
        float4 w3 = *(const float4*)&ws[k + 3][c0];
#pragma unroll
        for (int i = 0; i < RT; ++i) {
            float4 h4 = *(const float4*)&hs[r0 + i][k];
            acc[i][0] += h4.x * w0.x + h4.y * w1.x + h4.z * w2.x + h4.w * w3.x;
            acc[i][1] += h4.x * w0.y + h4.y * w1.y + h4.z * w2.y + h4.w * w3.y;
            acc[i][2] += h4.x * w0.z + h4.y * w1.z + h4.z * w2.z + h4.w * w3.z;
            acc[i][3] += h4.x * w0.w + h4.y * w1.w + h4.z * w2.w + h4.w * w3.w;
        }
    }

#pragma unroll
    for (int i = 0; i < RT; ++i) {
        int row = base + r0 + i;
        if (row < N_NODES) {
            float4 f = make_float4(acc[i][0], acc[i][1], acc[i][2], acc[i][3]);
            st4_half(out + (size_t)row * M + c0, f);
        }
    }
}

// ---------- SpMM (gather, no atomics) ----------
template <int M, bool RELU, bool DYNOUT>
__global__ __launch_bounds__(256) void spmm_kernel(const unsigned short* __restrict__ support,
                                                   const int* __restrict__ row_start,
                                                   const int2* __restrict__ csr_rec,
                                                   const void* __restrict__ bias,
                                                   void* __restrict__ out_,
                                                   const int* __restrict__ flagp) {
    constexpr int GROUP = M / 4;
    constexpr int GPB = 256 / GROUP;
    int bf = *flagp;
    int tid = threadIdx.x;
    int gid = blockIdx.x * GPB + tid / GROUP;
    int c0 = (tid % GROUP) * 4;
    if (gid >= N_NODES) return;
    int s = row_start[gid];
    int e = row_start[gid + 1];
    float a0 = ldf(bias, c0 + 0, bf);
    float a1 = ldf(bias, c0 + 1, bf);
    float a2 = ldf(bias, c0 + 2, bf);
    float a3 = ldf(bias, c0 + 3, bf);
    for (int j = s; j < e; ++j) {
        int2 rec = csr_rec[j];
        float v = __int_as_float(rec.y);
        float4 sp = ld4_half(support + (size_t)rec.x * M + c0);
        a0 += v * sp.x; a1 += v * sp.y; a2 += v * sp.z; a3 += v * sp.w;
    }
    if (RELU) {
        a0 = fmaxf(a0, 0.f); a1 = fmaxf(a1, 0.f);
        a2 = fmaxf(a2, 0.f); a3 = fmaxf(a3, 0.f);
    }
    float4 f = make_float4(a0, a1, a2, a3);
    if (DYNOUT) {
        if (bf) st4_half((unsigned short*)out_ + (size_t)gid * M + c0, f);
        else    *(float4*)((float*)out_ + (size_t)gid * M + c0) = f;
    } else {
        st4_half((unsigned short*)out_ + (size_t)gid * M + c0, f);
    }
}

extern "C" void kernel_launch(void* const* d_in, const int* in_sizes, int n_in,
                              void* d_out, int out_size, void* d_ws, size_t ws_size,
                              hipStream_t stream) {
    (void)in_sizes; (void)n_in; (void)out_size; (void)ws_size;
    const void* x  = d_in[0];
    const void* ev = d_in[1];
    const void* W1 = d_in[2];
    const void* b1 = d_in[3];
    const void* W2 = d_in[4];
    const void* b2 = d_in[5];
    const void* W3 = d_in[6];
    const void* b3 = d_in[7];
    const int* esrc = (const int*)d_in[8];
    const int* edst = (const int*)d_in[9];

    // workspace (~34 MB)
    char* ws = (char*)d_ws;
    size_t off = 0;
    auto alloc = [&](size_t bytes) -> void* {
        void* p = ws + off;
        off = (off + bytes + 255) & ~(size_t)255;
        return p;
    };
    unsigned short* A = (unsigned short*)alloc((size_t)N_NODES * 64 * 2);  // support (bf16)
    unsigned short* B = (unsigned short*)alloc((size_t)N_NODES * 64 * 2);  // agg (bf16)
    int* row_start  = (int*)alloc((size_t)(N_NODES + 1) * 4);
    int* bcount     = (int*)alloc(512);
    int* bstart     = (int*)alloc(512);
    int* bcursor    = (int*)alloc(512);
    int2* csr_rec   = (int2*)alloc((size_t)N_EDGES * 8);
    int* flagp      = (int*)alloc(256);
    // part[] (8 MB) aliases A (12.8 MB): only live before gemm1 writes A
    int2* part      = (int2*)A;

    // ---- dtype probe ----
    detect_kernel<<<1, 256, 0, stream>>>((const unsigned short*)x, flagp);

    // ---- bucket-local CSR build ----
    hipMemsetAsync(bcount, 0, 512, stream);
    bhist_kernel<<<(N_EDGES + 4095) / 4096, 256, 0, stream>>>(edst, bcount);
    bscan_kernel<<<1, 128, 0, stream>>>(bcount, bstart, bcursor);
    part_kernel<<<(N_EDGES + 2047) / 2048, 256, 0, stream>>>(esrc, edst, ev, bcursor, part, flagp);
    place_kernel<<<NBUCK, 512, 0, stream>>>(bstart, part, row_start, csr_rec);

    int g128 = (N_NODES + 31) / 32;
    int g64  = (N_NODES + 63) / 64;
    int gs64 = (N_NODES + 15) / 16;

    // ---- layer 1 ----
    gemm_kernel<128, 64, true><<<g128, 256, 0, stream>>>(x, W1, A, flagp);
    spmm_kernel<64, true, false><<<gs64, 256, 0, stream>>>(A, row_start, csr_rec, b1, B, flagp);
    // ---- layer 2 ----
    gemm_kernel<64, 64, false><<<g64, 256, 0, stream>>>(B, W2, A, flagp);
    spmm_kernel<64, true, false><<<gs64, 256, 0, stream>>>(A, row_start, csr_rec, b2, B, flagp);
    // ---- layer 3 ----
    gemm_kernel<64, 16, false><<<g64, 256, 0, stream>>>(B, W3, A, flagp);
    spmm_kernel<16, false, true><<<g64, 256, 0, stream>>>(A, row_start, csr_rec, b3, d_out, flagp);
}

// Round 6
// 313.020 us; speedup vs baseline: 1.4281x; 1.0420x over previous
//
#include <hip/hip_runtime.h>
#include <stdint.h>

#define N_NODES 100000
#define N_EDGES 1000000
#define NBUCK 98  // ceil(N_NODES / 1024)

typedef __attribute__((ext_vector_type(8))) __bf16 bf16x8;
typedef __attribute__((ext_vector_type(4))) float f32x4;

// ---------- bf16 helpers ----------
static __device__ __forceinline__ float bf2f(unsigned short u) {
    return __uint_as_float(((unsigned int)u) << 16);
}
static __device__ __forceinline__ unsigned short f2bf(float f) {
    unsigned int u = __float_as_uint(f);
    unsigned int r = (u + 0x7FFFu + ((u >> 16) & 1u)) >> 16;  // RNE
    return (unsigned short)r;
}
static __device__ __forceinline__ float4 ld4_half(const unsigned short* p) {
    ushort4 u = *(const ushort4*)p;
    return make_float4(bf2f(u.x), bf2f(u.y), bf2f(u.z), bf2f(u.w));
}
static __device__ __forceinline__ void st4_half(unsigned short* p, float4 f) {
    ushort4 u;
    u.x = f2bf(f.x); u.y = f2bf(f.y); u.z = f2bf(f.z); u.w = f2bf(f.w);
    *(ushort4*)p = u;
}

// ---------- dynamic-dtype external loads (flag: 1 = bf16 memory, 0 = f32) ----------
static __device__ __forceinline__ float ldf(const void* p, size_t i, int bf) {
    return bf ? bf2f(((const unsigned short*)p)[i]) : ((const float*)p)[i];
}
static __device__ __forceinline__ float4 ldf4(const void* p, size_t i, int bf) {
    if (bf) return ld4_half((const unsigned short*)p + i);
    return *(const float4*)((const float*)p + i);
}

// ---------- dtype probe ----------
__global__ __launch_bounds__(256) void detect_kernel(const unsigned short* __restrict__ xs,
                                                     int* __restrict__ flag) {
    __shared__ int sz;
    if (threadIdx.x == 0) sz = 0;
    __syncthreads();
    int z = 0;
    for (int i = threadIdx.x; i < 1024; i += 256) {
        float av = fabsf(bf2f(xs[2 * i]));
        if (!(av <= 1048576.0f) || (av != 0.0f && av < 9.5367431640625e-07f)) z++;
    }
    atomicAdd(&sz, z);
    __syncthreads();
    if (threadIdx.x == 0) *flag = (sz > 256) ? 0 : 1;
}

// ---------- CSR build, bucket-local ----------
__global__ __launch_bounds__(256) void bhist_kernel(const int* __restrict__ dst,
                                                    int* __restrict__ bcount) {
    __shared__ int cnt[NBUCK];
    int tid = threadIdx.x;
    for (int i = tid; i < NBUCK; i += 256) cnt[i] = 0;
    __syncthreads();
    int e0 = blockIdx.x * 4096;
#pragma unroll
    for (int i = 0; i < 16; ++i) {
        int e = e0 + i * 256 + tid;
        if (e < N_EDGES) atomicAdd(&cnt[dst[e] >> 10], 1);
    }
    __syncthreads();
    for (int i = tid; i < NBUCK; i += 256) {
        int c = cnt[i];
        if (c) atomicAdd(&bcount[i], c);
    }
}

__global__ __launch_bounds__(128) void bscan_kernel(const int* __restrict__ bcount,
                                                    int* __restrict__ bstart,
                                                    int* __restrict__ bcursor) {
    __shared__ int sh[128];
    int tid = threadIdx.x;
    int v = (tid < NBUCK) ? bcount[tid] : 0;
    sh[tid] = v;
    __syncthreads();
    for (int off = 1; off < 128; off <<= 1) {
        int t = 0;
        if (tid >= off) t = sh[tid - off];
        __syncthreads();
        if (tid >= off) sh[tid] += t;
        __syncthreads();
    }
    if (tid < NBUCK) {
        int excl = sh[tid] - v;
        bstart[tid] = excl;
        bcursor[tid] = excl;
    }
    if (tid == NBUCK - 1) bstart[NBUCK] = sh[tid];
}

__global__ __launch_bounds__(256) void part_kernel(const int* __restrict__ src,
                                                   const int* __restrict__ dst,
                                                   const void* __restrict__ val,
                                                   int* __restrict__ bcursor,
                                                   int2* __restrict__ part,
                                                   const int* __restrict__ flagp) {
    __shared__ int cnt[NBUCK];
    __shared__ int base[NBUCK];
    const int bf = *flagp;
    const int tid = threadIdx.x;
    const int e0 = blockIdx.x * 2048;
    for (int i = tid; i < NBUCK; i += 256) cnt[i] = 0;
    __syncthreads();
    int rank[8], bkt[8], pk[8], vb[8];
#pragma unroll
    for (int i = 0; i < 8; ++i) {
        int e = e0 + i * 256 + tid;
        bkt[i] = -1;
        if (e < N_EDGES) {
            int d = dst[e];
            int b = d >> 10;
            bkt[i] = b;
            pk[i] = src[e] | ((d & 1023) << 17);
            vb[i] = __float_as_int(ldf(val, e, bf));
            rank[i] = atomicAdd(&cnt[b], 1);
        }
    }
    __syncthreads();
    for (int i = tid; i < NBUCK; i += 256) {
        int c = cnt[i];
        base[i] = c ? atomicAdd(&bcursor[i], c) : 0;
    }
    __syncthreads();
#pragma unroll
    for (int i = 0; i < 8; ++i) {
        if (bkt[i] >= 0) part[(size_t)base[bkt[i]] + rank[i]] = make_int2(pk[i], vb[i]);
    }
}

__global__ __launch_bounds__(512) void place_kernel(const int* __restrict__ bstart,
                                                    const int2* __restrict__ part,
                                                    int* __restrict__ row_start,
                                                    int2* __restrict__ csr_rec) {
    __shared__ int cnt[1024];
    __shared__ int sums[512];
    const int tid = threadIdx.x;
    const int b = blockIdx.x;
    const int row0 = b << 10;
    const int nrows = min(1024, N_NODES - row0);
    const int s = bstart[b], e = bstart[b + 1];

    for (int i = tid; i < 1024; i += 512) cnt[i] = 0;
    __syncthreads();
    for (int j = s + tid; j < e; j += 512) {
        unsigned p = (unsigned)part[j].x;
        atomicAdd(&cnt[p >> 17], 1);
    }
    __syncthreads();
    int a0 = cnt[2 * tid], a1 = cnt[2 * tid + 1];
    int ts = a0 + a1;
    sums[tid] = ts;
    __syncthreads();
    for (int off = 1; off < 512; off <<= 1) {
        int t = 0;
        if (tid >= off) t = sums[tid - off];
        __syncthreads();
        if (tid >= off) sums[tid] += t;
        __syncthreads();
    }
    int excl = sums[tid] - ts;
    cnt[2 * tid] = s + excl;
    cnt[2 * tid + 1] = s + excl + a0;
    if (2 * tid < nrows)     row_start[row0 + 2 * tid] = s + excl;
    if (2 * tid + 1 < nrows) row_start[row0 + 2 * tid + 1] = s + excl + a0;
    if (b == NBUCK - 1 && tid == 0) row_start[N_NODES] = e;
    __syncthreads();
    for (int j = s + tid; j < e; j += 512) {
        int2 r = part[j];
        unsigned p = (unsigned)r.x;
        int pos = atomicAdd(&cnt[p >> 17], 1);
        csr_rec[pos] = make_int2((int)(p & 0x1FFFFu), r.y);
    }
}

// ---------- MFMA GEMM: out[N x M] = h[N x K] @ W[K x M], bf16 in, f32 acc, bf16 out ----------
// Block: 64 rows x M cols, 4 waves; wave w owns rows [w*16, w*16+16), all M cols.
// v_mfma_f32_16x16x32_bf16 layouts (guide-verified):
//   A[m=lane&15][k=quad*8+j], B[k=quad*8+j][n=lane&15], C: col=lane&15 row=quad*4+reg
template <int K, int M, bool DYNIN>
__global__ __launch_bounds__(256) void mgemm_kernel(const void* __restrict__ hv_,
                                                    const void* __restrict__ W,
                                                    unsigned short* __restrict__ out,
                                                    const int* __restrict__ flagp) {
    constexpr int LROWS = 64;
    constexpr int KP = K + 8;  // +16B pad: keeps 16B alignment, scatters banks
    constexpr int NC = M / 16; // column tiles per wave

    __shared__ unsigned short hs[LROWS][KP];
    __shared__ unsigned short wt[M][KP];  // W transposed: wt[m][k]

    const int bf = *flagp;
    const int tid = threadIdx.x;
    const int base = blockIdx.x * LROWS;

    // stage W transposed (external dtype -> bf16)
    for (int i = tid; i < K * M; i += 256) {
        int k = i / M, m = i % M;
        wt[m][k] = f2bf(ldf(W, i, bf));
    }
    // stage h tile -> bf16
    for (int i = tid * 4; i < LROWS * K; i += 1024) {
        int r = i / K;
        int kk = i & (K - 1);
        int grow = base + r;
        ushort4 u = make_ushort4(0, 0, 0, 0);
        if (grow < N_NODES) {
            if (DYNIN) {
                float4 f = ldf4(hv_, (size_t)grow * K + kk, bf);
                u.x = f2bf(f.x); u.y = f2bf(f.y); u.z = f2bf(f.z); u.w = f2bf(f.w);
            } else {
                u = *(const ushort4*)((const unsigned short*)hv_ + (size_t)grow * K + kk);
            }
        }
        *(ushort4*)&hs[r][kk] = u;
    }
    __syncthreads();

    const int wave = tid >> 6;
    const int lane = tid & 63;
    const int qd = lane >> 4;
    const int ln = lane & 15;
    const int wrow = wave * 16;

    f32x4 acc[NC];
#pragma unroll
    for (int c = 0; c < NC; ++c) acc[c] = (f32x4){0.f, 0.f, 0.f, 0.f};

#pragma unroll
    for (int k0 = 0; k0 < K; k0 += 32) {
        bf16x8 a = *(const bf16x8*)&hs[wrow + ln][k0 + qd * 8];
#pragma unroll
        for (int c = 0; c < NC; ++c) {
            bf16x8 b = *(const bf16x8*)&wt[c * 16 + ln][k0 + qd * 8];
            acc[c] = __builtin_amdgcn_mfma_f32_16x16x32_bf16(a, b, acc[c], 0, 0, 0);
        }
    }

#pragma unroll
    for (int c = 0; c < NC; ++c) {
#pragma unroll
        for (int r = 0; r < 4; ++r) {
            int row = base + wrow + qd * 4 + r;
            if (row < N_NODES) out[(size_t)row * M + c * 16 + ln] = f2bf(acc[c][r]);
        }
    }
}

// ---------- SpMM (gather, no atomics) ----------
template <int M, bool RELU, bool DYNOUT>
__global__ __launch_bounds__(256) void spmm_kernel(const unsigned short* __restrict__ support,
                                                   const int* __restrict__ row_start,
                                                   const int2* __restrict__ csr_rec,
                                                   const void* __restrict__ bias,
                                                   void* __restrict__ out_,
                                                   const int* __restrict__ flagp) {
    constexpr int GROUP = M / 4;
    constexpr int GPB = 256 / GROUP;
    int bf = *flagp;
    int tid = threadIdx.x;
    int gid = blockIdx.x * GPB + tid / GROUP;
    int c0 = (tid % GROUP) * 4;
    if (gid >= N_NODES) return;
    int s = row_start[gid];
    int e = row_start[gid + 1];
    float a0 = ldf(bias, c0 + 0, bf);
    float a1 = ldf(bias, c0 + 1, bf);
    float a2 = ldf(bias, c0 + 2, bf);
    float a3 = ldf(bias, c0 + 3, bf);
    for (int j = s; j < e; ++j) {
        int2 rec = csr_rec[j];
        float v = __int_as_float(rec.y);
        float4 sp = ld4_half(support + (size_t)rec.x * M + c0);
        a0 += v * sp.x; a1 += v * sp.y; a2 += v * sp.z; a3 += v * sp.w;
    }
    if (RELU) {
        a0 = fmaxf(a0, 0.f); a1 = fmaxf(a1, 0.f);
        a2 = fmaxf(a2, 0.f); a3 = fmaxf(a3, 0.f);
    }
    float4 f = make_float4(a0, a1, a2, a3);
    if (DYNOUT) {
        if (bf) st4_half((unsigned short*)out_ + (size_t)gid * M + c0, f);
        else    *(float4*)((float*)out_ + (size_t)gid * M + c0) = f;
    } else {
        st4_half((unsigned short*)out_ + (size_t)gid * M + c0, f);
    }
}

extern "C" void kernel_launch(void* const* d_in, const int* in_sizes, int n_in,
                              void* d_out, int out_size, void* d_ws, size_t ws_size,
                              hipStream_t stream) {
    (void)in_sizes; (void)n_in; (void)out_size; (void)ws_size;
    const void* x  = d_in[0];
    const void* ev = d_in[1];
    const void* W1 = d_in[2];
    const void* b1 = d_in[3];
    const void* W2 = d_in[4];
    const void* b2 = d_in[5];
    const void* W3 = d_in[6];
    const void* b3 = d_in[7];
    const int* esrc = (const int*)d_in[8];
    const int* edst = (const int*)d_in[9];

    // workspace (~34 MB)
    char* ws = (char*)d_ws;
    size_t off = 0;
    auto alloc = [&](size_t bytes) -> void* {
        void* p = ws + off;
        off = (off + bytes + 255) & ~(size_t)255;
        return p;
    };
    unsigned short* A = (unsigned short*)alloc((size_t)N_NODES * 64 * 2);  // support (bf16)
    unsigned short* B = (unsigned short*)alloc((size_t)N_NODES * 64 * 2);  // agg (bf16)
    int* row_start  = (int*)alloc((size_t)(N_NODES + 1) * 4);
    int* bcount     = (int*)alloc(512);
    int* bstart     = (int*)alloc(512);
    int* bcursor    = (int*)alloc(512);
    int2* csr_rec   = (int2*)alloc((size_t)N_EDGES * 8);
    int* flagp      = (int*)alloc(256);
    // part[] (8 MB) aliases A (12.8 MB): only live before gemm1 writes A
    int2* part      = (int2*)A;

    // ---- dtype probe ----
    detect_kernel<<<1, 256, 0, stream>>>((const unsigned short*)x, flagp);

    // ---- bucket-local CSR build ----
    hipMemsetAsync(bcount, 0, 512, stream);
    bhist_kernel<<<(N_EDGES + 4095) / 4096, 256, 0, stream>>>(edst, bcount);
    bscan_kernel<<<1, 128, 0, stream>>>(bcount, bstart, bcursor);
    part_kernel<<<(N_EDGES + 2047) / 2048, 256, 0, stream>>>(esrc, edst, ev, bcursor, part, flagp);
    place_kernel<<<NBUCK, 512, 0, stream>>>(bstart, part, row_start, csr_rec);

    int gm  = (N_NODES + 63) / 64;
    int gs64 = (N_NODES + 15) / 16;

    // ---- layer 1 ----
    mgemm_kernel<128, 64, true><<<gm, 256, 0, stream>>>(x, W1, A, flagp);
    spmm_kernel<64, true, false><<<gs64, 256, 0, stream>>>(A, row_start, csr_rec, b1, B, flagp);
    // ---- layer 2 ----
    mgemm_kernel<64, 64, false><<<gm, 256, 0, stream>>>(B, W2, A, flagp);
    spmm_kernel<64, true, false><<<gs64, 256, 0, stream>>>(A, row_start, csr_rec, b2, B, flagp);
    // ---- layer 3 ----
    mgemm_kernel<64, 16, false><<<gm, 256, 0, stream>>>(B, W3, A, flagp);
    spmm_kernel<16, false, true><<<gm, 256, 0, stream>>>(A, row_start, csr_rec, b3, d_out, flagp);
}

// Round 7
// 282.141 us; speedup vs baseline: 1.5844x; 1.1094x over previous
//
#include <hip/hip_runtime.h>
#include <stdint.h>

#define N_NODES 100000
#define N_EDGES 1000000
#define NBUCK 98  // ceil(N_NODES / 1024)

typedef __attribute__((ext_vector_type(8))) __bf16 bf16x8;
typedef __attribute__((ext_vector_type(4))) float f32x4;

// ---------- bf16 helpers ----------
static __device__ __forceinline__ float bf2f(unsigned short u) {
    return __uint_as_float(((unsigned int)u) << 16);
}
static __device__ __forceinline__ unsigned short f2bf(float f) {
    unsigned int u = __float_as_uint(f);
    unsigned int r = (u + 0x7FFFu + ((u >> 16) & 1u)) >> 16;  // RNE
    return (unsigned short)r;
}
static __device__ __forceinline__ float4 ld4_half(const unsigned short* p) {
    ushort4 u = *(const ushort4*)p;
    return make_float4(bf2f(u.x), bf2f(u.y), bf2f(u.z), bf2f(u.w));
}
static __device__ __forceinline__ void st4_half(unsigned short* p, float4 f) {
    ushort4 u;
    u.x = f2bf(f.x); u.y = f2bf(f.y); u.z = f2bf(f.z); u.w = f2bf(f.w);
    *(ushort4*)p = u;
}

// ---------- dynamic-dtype external loads (flag: 1 = bf16 memory, 0 = f32) ----------
static __device__ __forceinline__ float ldf(const void* p, size_t i, int bf) {
    return bf ? bf2f(((const unsigned short*)p)[i]) : ((const float*)p)[i];
}
static __device__ __forceinline__ float4 ldf4(const void* p, size_t i, int bf) {
    if (bf) return ld4_half((const unsigned short*)p + i);
    return *(const float4*)((const float*)p + i);
}

// ---------- dtype probe ----------
__global__ __launch_bounds__(256) void detect_kernel(const unsigned short* __restrict__ xs,
                                                     int* __restrict__ flag) {
    __shared__ int sz;
    if (threadIdx.x == 0) sz = 0;
    __syncthreads();
    int z = 0;
    for (int i = threadIdx.x; i < 1024; i += 256) {
        float av = fabsf(bf2f(xs[2 * i]));
        if (!(av <= 1048576.0f) || (av != 0.0f && av < 9.5367431640625e-07f)) z++;
    }
    atomicAdd(&sz, z);
    __syncthreads();
    if (threadIdx.x == 0) *flag = (sz > 256) ? 0 : 1;
}

// ---------- CSR build, bucket-local ----------
__global__ __launch_bounds__(256) void bhist_kernel(const int* __restrict__ dst,
                                                    int* __restrict__ bcount) {
    __shared__ int cnt[NBUCK];
    int tid = threadIdx.x;
    for (int i = tid; i < NBUCK; i += 256) cnt[i] = 0;
    __syncthreads();
    int e0 = blockIdx.x * 4096;
#pragma unroll
    for (int i = 0; i < 16; ++i) {
        int e = e0 + i * 256 + tid;
        if (e < N_EDGES) atomicAdd(&cnt[dst[e] >> 10], 1);
    }
    __syncthreads();
    for (int i = tid; i < NBUCK; i += 256) {
        int c = cnt[i];
        if (c) atomicAdd(&bcount[i], c);
    }
}

__global__ __launch_bounds__(128) void bscan_kernel(const int* __restrict__ bcount,
                                                    int* __restrict__ bstart,
                                                    int* __restrict__ bcursor) {
    __shared__ int sh[128];
    int tid = threadIdx.x;
    int v = (tid < NBUCK) ? bcount[tid] : 0;
    sh[tid] = v;
    __syncthreads();
    for (int off = 1; off < 128; off <<= 1) {
        int t = 0;
        if (tid >= off) t = sh[tid - off];
        __syncthreads();
        if (tid >= off) sh[tid] += t;
        __syncthreads();
    }
    if (tid < NBUCK) {
        int excl = sh[tid] - v;
        bstart[tid] = excl;
        bcursor[tid] = excl;
    }
    if (tid == NBUCK - 1) bstart[NBUCK] = sh[tid];
}

__global__ __launch_bounds__(256) void part_kernel(const int* __restrict__ src,
                                                   const int* __restrict__ dst,
                                                   const void* __restrict__ val,
                                                   int* __restrict__ bcursor,
                                                   int2* __restrict__ part,
                                                   const int* __restrict__ flagp) {
    __shared__ int cnt[NBUCK];
    __shared__ int base[NBUCK];
    const int bf = *flagp;
    const int tid = threadIdx.x;
    const int e0 = blockIdx.x * 2048;
    for (int i = tid; i < NBUCK; i += 256) cnt[i] = 0;
    __syncthreads();
    int rank[8], bkt[8], pk[8], vb[8];
#pragma unroll
    for (int i = 0; i < 8; ++i) {
        int e = e0 + i * 256 + tid;
        bkt[i] = -1;
        if (e < N_EDGES) {
            int d = dst[e];
            int b = d >> 10;
            bkt[i] = b;
            pk[i] = src[e] | ((d & 1023) << 17);
            vb[i] = __float_as_int(ldf(val, e, bf));
            rank[i] = atomicAdd(&cnt[b], 1);
        }
    }
    __syncthreads();
    for (int i = tid; i < NBUCK; i += 256) {
        int c = cnt[i];
        base[i] = c ? atomicAdd(&bcursor[i], c) : 0;
    }
    __syncthreads();
#pragma unroll
    for (int i = 0; i < 8; ++i) {
        if (bkt[i] >= 0) part[(size_t)base[bkt[i]] + rank[i]] = make_int2(pk[i], vb[i]);
    }
}

__global__ __launch_bounds__(512) void place_kernel(const int* __restrict__ bstart,
                                                    const int2* __restrict__ part,
                                                    int* __restrict__ row_start,
                                                    int2* __restrict__ csr_rec) {
    __shared__ int cnt[1024];
    __shared__ int sums[512];
    const int tid = threadIdx.x;
    const int b = blockIdx.x;
    const int row0 = b << 10;
    const int nrows = min(1024, N_NODES - row0);
    const int s = bstart[b], e = bstart[b + 1];

    for (int i = tid; i < 1024; i += 512) cnt[i] = 0;
    __syncthreads();
    for (int j = s + tid; j < e; j += 512) {
        unsigned p = (unsigned)part[j].x;
        atomicAdd(&cnt[p >> 17], 1);
    }
    __syncthreads();
    int a0 = cnt[2 * tid], a1 = cnt[2 * tid + 1];
    int ts = a0 + a1;
    sums[tid] = ts;
    __syncthreads();
    for (int off = 1; off < 512; off <<= 1) {
        int t = 0;
        if (tid >= off) t = sums[tid - off];
        __syncthreads();
        if (tid >= off) sums[tid] += t;
        __syncthreads();
    }
    int excl = sums[tid] - ts;
    cnt[2 * tid] = s + excl;
    cnt[2 * tid + 1] = s + excl + a0;
    if (2 * tid < nrows)     row_start[row0 + 2 * tid] = s + excl;
    if (2 * tid + 1 < nrows) row_start[row0 + 2 * tid + 1] = s + excl + a0;
    if (b == NBUCK - 1 && tid == 0) row_start[N_NODES] = e;
    __syncthreads();
    for (int j = s + tid; j < e; j += 512) {
        int2 r = part[j];
        unsigned p = (unsigned)r.x;
        int pos = atomicAdd(&cnt[p >> 17], 1);
        csr_rec[pos] = make_int2((int)(p & 0x1FFFFu), r.y);
    }
}

// ---------- MFMA GEMM: out[N x M] = h[N x K] @ W[K x M], bf16 in, f32 acc, bf16 out ----------
template <int K, int M, bool DYNIN>
__global__ __launch_bounds__(256) void mgemm_kernel(const void* __restrict__ hv_,
                                                    const void* __restrict__ W,
                                                    unsigned short* __restrict__ out,
                                                    const int* __restrict__ flagp) {
    constexpr int LROWS = 64;
    constexpr int KP = K + 8;
    constexpr int NC = M / 16;

    __shared__ unsigned short hs[LROWS][KP];
    __shared__ unsigned short wt[M][KP];  // W transposed: wt[m][k]

    const int bf = *flagp;
    const int tid = threadIdx.x;
    const int base = blockIdx.x * LROWS;

    for (int i = tid; i < K * M; i += 256) {
        int k = i / M, m = i % M;
        wt[m][k] = f2bf(ldf(W, i, bf));
    }
    for (int i = tid * 4; i < LROWS * K; i += 1024) {
        int r = i / K;
        int kk = i & (K - 1);
        int grow = base + r;
        ushort4 u = make_ushort4(0, 0, 0, 0);
        if (grow < N_NODES) {
            if (DYNIN) {
                float4 f = ldf4(hv_, (size_t)grow * K + kk, bf);
                u.x = f2bf(f.x); u.y = f2bf(f.y); u.z = f2bf(f.z); u.w = f2bf(f.w);
            } else {
                u = *(const ushort4*)((const unsigned short*)hv_ + (size_t)grow * K + kk);
            }
        }
        *(ushort4*)&hs[r][kk] = u;
    }
    __syncthreads();

    const int wave = tid >> 6;
    const int lane = tid & 63;
    const int qd = lane >> 4;
    const int ln = lane & 15;
    const int wrow = wave * 16;

    f32x4 acc[NC];
#pragma unroll
    for (int c = 0; c < NC; ++c) acc[c] = (f32x4){0.f, 0.f, 0.f, 0.f};

#pragma unroll
    for (int k0 = 0; k0 < K; k0 += 32) {
        bf16x8 a = *(const bf16x8*)&hs[wrow + ln][k0 + qd * 8];
#pragma unroll
        for (int c = 0; c < NC; ++c) {
            bf16x8 b = *(const bf16x8*)&wt[c * 16 + ln][k0 + qd * 8];
            acc[c] = __builtin_amdgcn_mfma_f32_16x16x32_bf16(a, b, acc[c], 0, 0, 0);
        }
    }

#pragma unroll
    for (int c = 0; c < NC; ++c) {
#pragma unroll
        for (int r = 0; r < 4; ++r) {
            int row = base + wrow + qd * 4 + r;
            if (row < N_NODES) out[(size_t)row * M + c * 16 + ln] = f2bf(acc[c][r]);
        }
    }
}

// ---------- SpMM (gather, no atomics), 4-wide unrolled for MLP ----------
template <int M, bool RELU, bool DYNOUT>
__global__ __launch_bounds__(256) void spmm_kernel(const unsigned short* __restrict__ support,
                                                   const int* __restrict__ row_start,
                                                   const int2* __restrict__ csr_rec,
                                                   const void* __restrict__ bias,
                                                   void* __restrict__ out_,
                                                   const int* __restrict__ flagp) {
    constexpr int GROUP = M / 4;
    constexpr int GPB = 256 / GROUP;
    int bf = *flagp;
    int tid = threadIdx.x;
    int gid = blockIdx.x * GPB + tid / GROUP;
    int c0 = (tid % GROUP) * 4;
    if (gid >= N_NODES) return;
    int s = row_start[gid];
    int e = row_start[gid + 1];
    float a0 = ldf(bias, c0 + 0, bf);
    float a1 = ldf(bias, c0 + 1, bf);
    float a2 = ldf(bias, c0 + 2, bf);
    float a3 = ldf(bias, c0 + 3, bf);
    const unsigned short* supc = support + c0;

    int j = s;
    // 4-wide: 4 independent rec loads, then 4 independent gathers in flight.
    // Accumulation stays in edge order (bit-identical to the scalar loop).
    for (; j + 3 < e; j += 4) {
        int2 r0 = csr_rec[j + 0];
        int2 r1 = csr_rec[j + 1];
        int2 r2 = csr_rec[j + 2];
        int2 r3 = csr_rec[j + 3];
        float4 s0 = ld4_half(supc + (size_t)r0.x * M);
        float4 s1 = ld4_half(supc + (size_t)r1.x * M);
        float4 s2 = ld4_half(supc + (size_t)r2.x * M);
        float4 s3 = ld4_half(supc + (size_t)r3.x * M);
        float v0 = __int_as_float(r0.y);
        float v1 = __int_as_float(r1.y);
        float v2 = __int_as_float(r2.y);
        float v3 = __int_as_float(r3.y);
        a0 += v0 * s0.x; a1 += v0 * s0.y; a2 += v0 * s0.z; a3 += v0 * s0.w;
        a0 += v1 * s1.x; a1 += v1 * s1.y; a2 += v1 * s1.z; a3 += v1 * s1.w;
        a0 += v2 * s2.x; a1 += v2 * s2.y; a2 += v2 * s2.z; a3 += v2 * s2.w;
        a0 += v3 * s3.x; a1 += v3 * s3.y; a2 += v3 * s3.z; a3 += v3 * s3.w;
    }
    for (; j < e; ++j) {
        int2 rec = csr_rec[j];
        float v = __int_as_float(rec.y);
        float4 sp = ld4_half(supc + (size_t)rec.x * M);
        a0 += v * sp.x; a1 += v * sp.y; a2 += v * sp.z; a3 += v * sp.w;
    }
    if (RELU) {
        a0 = fmaxf(a0, 0.f); a1 = fmaxf(a1, 0.f);
        a2 = fmaxf(a2, 0.f); a3 = fmaxf(a3, 0.f);
    }
    float4 f = make_float4(a0, a1, a2, a3);
    if (DYNOUT) {
        if (bf) st4_half((unsigned short*)out_ + (size_t)gid * M + c0, f);
        else    *(float4*)((float*)out_ + (size_t)gid * M + c0) = f;
    } else {
        st4_half((unsigned short*)out_ + (size_t)gid * M + c0, f);
    }
}

extern "C" void kernel_launch(void* const* d_in, const int* in_sizes, int n_in,
                              void* d_out, int out_size, void* d_ws, size_t ws_size,
                              hipStream_t stream) {
    (void)in_sizes; (void)n_in; (void)out_size; (void)ws_size;
    const void* x  = d_in[0];
    const void* ev = d_in[1];
    const void* W1 = d_in[2];
    const void* b1 = d_in[3];
    const void* W2 = d_in[4];
    const void* b2 = d_in[5];
    const void* W3 = d_in[6];
    const void* b3 = d_in[7];
    const int* esrc = (const int*)d_in[8];
    const int* edst = (const int*)d_in[9];

    // workspace (~34 MB)
    char* ws = (char*)d_ws;
    size_t off = 0;
    auto alloc = [&](size_t bytes) -> void* {
        void* p = ws + off;
        off = (off + bytes + 255) & ~(size_t)255;
        return p;
    };
    unsigned short* A = (unsigned short*)alloc((size_t)N_NODES * 64 * 2);  // support (bf16)
    unsigned short* B = (unsigned short*)alloc((size_t)N_NODES * 64 * 2);  // agg (bf16)
    int* row_start  = (int*)alloc((size_t)(N_NODES + 1) * 4);
    int* bcount     = (int*)alloc(512);
    int* bstart     = (int*)alloc(512);
    int* bcursor    = (int*)alloc(512);
    int2* csr_rec   = (int2*)alloc((size_t)N_EDGES * 8);
    int* flagp      = (int*)alloc(256);
    // part[] (8 MB) aliases A (12.8 MB): only live before gemm1 writes A
    int2* part      = (int2*)A;

    // ---- dtype probe ----
    detect_kernel<<<1, 256, 0, stream>>>((const unsigned short*)x, flagp);

    // ---- bucket-local CSR build ----
    hipMemsetAsync(bcount, 0, 512, stream);
    bhist_kernel<<<(N_EDGES + 4095) / 4096, 256, 0, stream>>>(edst, bcount);
    bscan_kernel<<<1, 128, 0, stream>>>(bcount, bstart, bcursor);
    part_kernel<<<(N_EDGES + 2047) / 2048, 256, 0, stream>>>(esrc, edst, ev, bcursor, part, flagp);
    place_kernel<<<NBUCK, 512, 0, stream>>>(bstart, part, row_start, csr_rec);

    int gm  = (N_NODES + 63) / 64;
    int gs64 = (N_NODES + 15) / 16;

    // ---- layer 1 ----
    mgemm_kernel<128, 64, true><<<gm, 256, 0, stream>>>(x, W1, A, flagp);
    spmm_kernel<64, true, false><<<gs64, 256, 0, stream>>>(A, row_start, csr_rec, b1, B, flagp);
    // ---- layer 2 ----
    mgemm_kernel<64, 64, false><<<gm, 256, 0, stream>>>(B, W2, A, flagp);
    spmm_kernel<64, true, false><<<gs64, 256, 0, stream>>>(A, row_start, csr_rec, b2, B, flagp);
    // ---- layer 3 ----
    mgemm_kernel<64, 16, false><<<gm, 256, 0, stream>>>(B, W3, A, flagp);
    spmm_kernel<16, false, true><<<gm, 256, 0, stream>>>(A, row_start, csr_rec, b3, d_out, flagp);
}

// Round 8
// 277.333 us; speedup vs baseline: 1.6118x; 1.0173x over previous
//
#include <hip/hip_runtime.h>
#include <stdint.h>

#define N_NODES 100000
#define N_EDGES 1000000
#define NBUCK 98  // ceil(N_NODES / 1024)

typedef __attribute__((ext_vector_type(8))) __bf16 bf16x8;
typedef __attribute__((ext_vector_type(4))) float f32x4;

// ---------- bf16 helpers ----------
static __device__ __forceinline__ float bf2f(unsigned short u) {
    return __uint_as_float(((unsigned int)u) << 16);
}
static __device__ __forceinline__ unsigned short f2bf(float f) {
    unsigned int u = __float_as_uint(f);
    unsigned int r = (u + 0x7FFFu + ((u >> 16) & 1u)) >> 16;  // RNE
    return (unsigned short)r;
}
static __device__ __forceinline__ float4 ld4_half(const unsigned short* p) {
    ushort4 u = *(const ushort4*)p;
    return make_float4(bf2f(u.x), bf2f(u.y), bf2f(u.z), bf2f(u.w));
}
static __device__ __forceinline__ void st4_half(unsigned short* p, float4 f) {
    ushort4 u;
    u.x = f2bf(f.x); u.y = f2bf(f.y); u.z = f2bf(f.z); u.w = f2bf(f.w);
    *(ushort4*)p = u;
}

// ---------- dynamic-dtype external loads (flag: 1 = bf16 memory, 0 = f32) ----------
static __device__ __forceinline__ float ldf(const void* p, size_t i, int bf) {
    return bf ? bf2f(((const unsigned short*)p)[i]) : ((const float*)p)[i];
}
static __device__ __forceinline__ float4 ldf4(const void* p, size_t i, int bf) {
    if (bf) return ld4_half((const unsigned short*)p + i);
    return *(const float4*)((const float*)p + i);
}

// ---------- dtype probe ----------
__global__ __launch_bounds__(256) void detect_kernel(const unsigned short* __restrict__ xs,
                                                     int* __restrict__ flag) {
    __shared__ int sz;
    if (threadIdx.x == 0) sz = 0;
    __syncthreads();
    int z = 0;
    for (int i = threadIdx.x; i < 1024; i += 256) {
        float av = fabsf(bf2f(xs[2 * i]));
        if (!(av <= 1048576.0f) || (av != 0.0f && av < 9.5367431640625e-07f)) z++;
    }
    atomicAdd(&sz, z);
    __syncthreads();
    if (threadIdx.x == 0) *flag = (sz > 256) ? 0 : 1;
}

// ---------- CSR build, bucket-local ----------
__global__ __launch_bounds__(256) void bhist_kernel(const int* __restrict__ dst,
                                                    int* __restrict__ bcount) {
    __shared__ int cnt[NBUCK];
    int tid = threadIdx.x;
    for (int i = tid; i < NBUCK; i += 256) cnt[i] = 0;
    __syncthreads();
    int e0 = blockIdx.x * 4096;
#pragma unroll
    for (int i = 0; i < 16; ++i) {
        int e = e0 + i * 256 + tid;
        if (e < N_EDGES) atomicAdd(&cnt[dst[e] >> 10], 1);
    }
    __syncthreads();
    for (int i = tid; i < NBUCK; i += 256) {
        int c = cnt[i];
        if (c) atomicAdd(&bcount[i], c);
    }
}

__global__ __launch_bounds__(128) void bscan_kernel(const int* __restrict__ bcount,
                                                    int* __restrict__ bstart,
                                                    int* __restrict__ bcursor) {
    __shared__ int sh[128];
    int tid = threadIdx.x;
    int v = (tid < NBUCK) ? bcount[tid] : 0;
    sh[tid] = v;
    __syncthreads();
    for (int off = 1; off < 128; off <<= 1) {
        int t = 0;
        if (tid >= off) t = sh[tid - off];
        __syncthreads();
        if (tid >= off) sh[tid] += t;
        __syncthreads();
    }
    if (tid < NBUCK) {
        int excl = sh[tid] - v;
        bstart[tid] = excl;
        bcursor[tid] = excl;
    }
    if (tid == NBUCK - 1) bstart[NBUCK] = sh[tid];
}

__global__ __launch_bounds__(256) void part_kernel(const int* __restrict__ src,
                                                   const int* __restrict__ dst,
                                                   const void* __restrict__ val,
                                                   int* __restrict__ bcursor,
                                                   int2* __restrict__ part,
                                                   const int* __restrict__ flagp) {
    __shared__ int cnt[NBUCK];
    __shared__ int base[NBUCK];
    const int bf = *flagp;
    const int tid = threadIdx.x;
    const int e0 = blockIdx.x * 2048;
    for (int i = tid; i < NBUCK; i += 256) cnt[i] = 0;
    __syncthreads();
    int rank[8], bkt[8], pk[8], vb[8];
#pragma unroll
    for (int i = 0; i < 8; ++i) {
        int e = e0 + i * 256 + tid;
        bkt[i] = -1;
        if (e < N_EDGES) {
            int d = dst[e];
            int b = d >> 10;
            bkt[i] = b;
            pk[i] = src[e] | ((d & 1023) << 17);
            vb[i] = __float_as_int(ldf(val, e, bf));
            rank[i] = atomicAdd(&cnt[b], 1);
        }
    }
    __syncthreads();
    for (int i = tid; i < NBUCK; i += 256) {
        int c = cnt[i];
        base[i] = c ? atomicAdd(&bcursor[i], c) : 0;
    }
    __syncthreads();
#pragma unroll
    for (int i = 0; i < 8; ++i) {
        if (bkt[i] >= 0) part[(size_t)base[bkt[i]] + rank[i]] = make_int2(pk[i], vb[i]);
    }
}

__global__ __launch_bounds__(512) void place_kernel(const int* __restrict__ bstart,
                                                    const int2* __restrict__ part,
                                                    int* __restrict__ row_start,
                                                    int2* __restrict__ csr_rec) {
    __shared__ int cnt[1024];
    __shared__ int sums[512];
    const int tid = threadIdx.x;
    const int b = blockIdx.x;
    const int row0 = b << 10;
    const int nrows = min(1024, N_NODES - row0);
    const int s = bstart[b], e = bstart[b + 1];

    for (int i = tid; i < 1024; i += 512) cnt[i] = 0;
    __syncthreads();
    for (int j = s + tid; j < e; j += 512) {
        unsigned p = (unsigned)part[j].x;
        atomicAdd(&cnt[p >> 17], 1);
    }
    __syncthreads();
    int a0 = cnt[2 * tid], a1 = cnt[2 * tid + 1];
    int ts = a0 + a1;
    sums[tid] = ts;
    __syncthreads();
    for (int off = 1; off < 512; off <<= 1) {
        int t = 0;
        if (tid >= off) t = sums[tid - off];
        __syncthreads();
        if (tid >= off) sums[tid] += t;
        __syncthreads();
    }
    int excl = sums[tid] - ts;
    cnt[2 * tid] = s + excl;
    cnt[2 * tid + 1] = s + excl + a0;
    if (2 * tid < nrows)     row_start[row0 + 2 * tid] = s + excl;
    if (2 * tid + 1 < nrows) row_start[row0 + 2 * tid + 1] = s + excl + a0;
    if (b == NBUCK - 1 && tid == 0) row_start[N_NODES] = e;
    __syncthreads();
    for (int j = s + tid; j < e; j += 512) {
        int2 r = part[j];
        unsigned p = (unsigned)r.x;
        int pos = atomicAdd(&cnt[p >> 17], 1);
        csr_rec[pos] = make_int2((int)(p & 0x1FFFFu), r.y);
    }
}

// ---------- MFMA GEMM v2: A direct from global (no reuse -> no LDS), B in registers ----------
// W staged once per block into LDS (transposed), then hoisted to VGPR fragments.
// Grid-stride over 64-row tiles. No barriers in the tile loop.
template <int K, int M, bool DYNIN>
__global__ __launch_bounds__(256, 4) void mgemm_kernel(const void* __restrict__ hv_,
                                                       const void* __restrict__ W,
                                                       unsigned short* __restrict__ out,
                                                       const int* __restrict__ flagp) {
    constexpr int KP = K + 8;   // pad keeps b128 reads ~conflict-free
    constexpr int NC = M / 16;  // column tiles per wave
    constexpr int NK = K / 32;  // k-steps
    constexpr int NT = (N_NODES + 63) / 64;

    __shared__ unsigned short wt[M][KP];  // W transposed: wt[m][k]

    const int bf = *flagp;
    const int tid = threadIdx.x;

    // stage W transposed (once per block)
    for (int i = tid; i < K * M; i += 256) {
        int k = i / M, m = i % M;
        wt[m][k] = f2bf(ldf(W, i, bf));
    }
    __syncthreads();

    const int lane = tid & 63;
    const int qd = lane >> 4;
    const int ln = lane & 15;
    const int wrow = (tid >> 6) * 16;  // wave's 16-row stripe within the 64-row tile

    // hoist all B fragments to registers: bfrag[k-step][c]
    bf16x8 bfrag[NK][NC];
#pragma unroll
    for (int ks = 0; ks < NK; ++ks)
#pragma unroll
        for (int c = 0; c < NC; ++c)
            bfrag[ks][c] = *(const bf16x8*)&wt[c * 16 + ln][ks * 32 + qd * 8];

    for (int tile = blockIdx.x; tile < NT; tile += gridDim.x) {
        const int row = tile * 64 + wrow + ln;   // A-row this lane feeds
        const bool ok = row < N_NODES;

        f32x4 acc[NC];
#pragma unroll
        for (int c = 0; c < NC; ++c) acc[c] = (f32x4){0.f, 0.f, 0.f, 0.f};

#pragma unroll
        for (int ks = 0; ks < NK; ++ks) {
            bf16x8 a;
            if (ok) {
                const size_t base = (size_t)row * K + ks * 32 + qd * 8;
                if (DYNIN && !bf) {
                    const float* xp = (const float*)hv_ + base;
                    float4 f0 = *(const float4*)xp;
                    float4 f1 = *(const float4*)(xp + 4);
                    ushort4 u0, u1;
                    u0.x = f2bf(f0.x); u0.y = f2bf(f0.y); u0.z = f2bf(f0.z); u0.w = f2bf(f0.w);
                    u1.x = f2bf(f1.x); u1.y = f2bf(f1.y); u1.z = f2bf(f1.z); u1.w = f2bf(f1.w);
                    ushort4 uu[2] = {u0, u1};
                    a = *(const bf16x8*)uu;
                } else {
                    a = *(const bf16x8*)((const unsigned short*)hv_ + base);
                }
            } else {
                a = (bf16x8)(__bf16)0.0f;
            }
#pragma unroll
            for (int c = 0; c < NC; ++c)
                acc[c] = __builtin_amdgcn_mfma_f32_16x16x32_bf16(a, bfrag[ks][c], acc[c], 0, 0, 0);
        }

#pragma unroll
        for (int c = 0; c < NC; ++c) {
#pragma unroll
            for (int r = 0; r < 4; ++r) {
                int orow = tile * 64 + wrow + qd * 4 + r;
                if (orow < N_NODES) out[(size_t)orow * M + c * 16 + ln] = f2bf(acc[c][r]);
            }
        }
    }
}

// ---------- SpMM (gather, no atomics), 4-wide unrolled for MLP ----------
template <int M, bool RELU, bool DYNOUT>
__global__ __launch_bounds__(256) void spmm_kernel(const unsigned short* __restrict__ support,
                                                   const int* __restrict__ row_start,
                                                   const int2* __restrict__ csr_rec,
                                                   const void* __restrict__ bias,
                                                   void* __restrict__ out_,
                                                   const int* __restrict__ flagp) {
    constexpr int GROUP = M / 4;
    constexpr int GPB = 256 / GROUP;
    int bf = *flagp;
    int tid = threadIdx.x;
    int gid = blockIdx.x * GPB + tid / GROUP;
    int c0 = (tid % GROUP) * 4;
    if (gid >= N_NODES) return;
    int s = row_start[gid];
    int e = row_start[gid + 1];
    float a0 = ldf(bias, c0 + 0, bf);
    float a1 = ldf(bias, c0 + 1, bf);
    float a2 = ldf(bias, c0 + 2, bf);
    float a3 = ldf(bias, c0 + 3, bf);
    const unsigned short* supc = support + c0;

    int j = s;
    for (; j + 3 < e; j += 4) {
        int2 r0 = csr_rec[j + 0];
        int2 r1 = csr_rec[j + 1];
        int2 r2 = csr_rec[j + 2];
        int2 r3 = csr_rec[j + 3];
        float4 s0 = ld4_half(supc + (size_t)r0.x * M);
        float4 s1 = ld4_half(supc + (size_t)r1.x * M);
        float4 s2 = ld4_half(supc + (size_t)r2.x * M);
        float4 s3 = ld4_half(supc + (size_t)r3.x * M);
        float v0 = __int_as_float(r0.y);
        float v1 = __int_as_float(r1.y);
        float v2 = __int_as_float(r2.y);
        float v3 = __int_as_float(r3.y);
        a0 += v0 * s0.x; a1 += v0 * s0.y; a2 += v0 * s0.z; a3 += v0 * s0.w;
        a0 += v1 * s1.x; a1 += v1 * s1.y; a2 += v1 * s1.z; a3 += v1 * s1.w;
        a0 += v2 * s2.x; a1 += v2 * s2.y; a2 += v2 * s2.z; a3 += v2 * s2.w;
        a0 += v3 * s3.x; a1 += v3 * s3.y; a2 += v3 * s3.z; a3 += v3 * s3.w;
    }
    for (; j < e; ++j) {
        int2 rec = csr_rec[j];
        float v = __int_as_float(rec.y);
        float4 sp = ld4_half(supc + (size_t)rec.x * M);
        a0 += v * sp.x; a1 += v * sp.y; a2 += v * sp.z; a3 += v * sp.w;
    }
    if (RELU) {
        a0 = fmaxf(a0, 0.f); a1 = fmaxf(a1, 0.f);
        a2 = fmaxf(a2, 0.f); a3 = fmaxf(a3, 0.f);
    }
    float4 f = make_float4(a0, a1, a2, a3);
    if (DYNOUT) {
        if (bf) st4_half((unsigned short*)out_ + (size_t)gid * M + c0, f);
        else    *(float4*)((float*)out_ + (size_t)gid * M + c0) = f;
    } else {
        st4_half((unsigned short*)out_ + (size_t)gid * M + c0, f);
    }
}

extern "C" void kernel_launch(void* const* d_in, const int* in_sizes, int n_in,
                              void* d_out, int out_size, void* d_ws, size_t ws_size,
                              hipStream_t stream) {
    (void)in_sizes; (void)n_in; (void)out_size; (void)ws_size;
    const void* x  = d_in[0];
    const void* ev = d_in[1];
    const void* W1 = d_in[2];
    const void* b1 = d_in[3];
    const void* W2 = d_in[4];
    const void* b2 = d_in[5];
    const void* W3 = d_in[6];
    const void* b3 = d_in[7];
    const int* esrc = (const int*)d_in[8];
    const int* edst = (const int*)d_in[9];

    // workspace (~34 MB)
    char* ws = (char*)d_ws;
    size_t off = 0;
    auto alloc = [&](size_t bytes) -> void* {
        void* p = ws + off;
        off = (off + bytes + 255) & ~(size_t)255;
        return p;
    };
    unsigned short* A = (unsigned short*)alloc((size_t)N_NODES * 64 * 2);  // support (bf16)
    unsigned short* B = (unsigned short*)alloc((size_t)N_NODES * 64 * 2);  // agg (bf16)
    int* row_start  = (int*)alloc((size_t)(N_NODES + 1) * 4);
    int* bcount     = (int*)alloc(512);
    int* bstart     = (int*)alloc(512);
    int* bcursor    = (int*)alloc(512);
    int2* csr_rec   = (int2*)alloc((size_t)N_EDGES * 8);
    int* flagp      = (int*)alloc(256);
    // part[] (8 MB) aliases A (12.8 MB): only live before gemm1 writes A
    int2* part      = (int2*)A;

    // ---- dtype probe ----
    detect_kernel<<<1, 256, 0, stream>>>((const unsigned short*)x, flagp);

    // ---- bucket-local CSR build ----
    hipMemsetAsync(bcount, 0, 512, stream);
    bhist_kernel<<<(N_EDGES + 4095) / 4096, 256, 0, stream>>>(edst, bcount);
    bscan_kernel<<<1, 128, 0, stream>>>(bcount, bstart, bcursor);
    part_kernel<<<(N_EDGES + 2047) / 2048, 256, 0, stream>>>(esrc, edst, ev, bcursor, part, flagp);
    place_kernel<<<NBUCK, 512, 0, stream>>>(bstart, part, row_start, csr_rec);

    int gm   = 1024;  // grid-stride tiles; 4 blocks/CU via __launch_bounds__(256,4)
    int gs64 = (N_NODES + 15) / 16;
    int g64  = (N_NODES + 63) / 64;

    // ---- layer 1 ----
    mgemm_kernel<128, 64, true><<<gm, 256, 0, stream>>>(x, W1, A, flagp);
    spmm_kernel<64, true, false><<<gs64, 256, 0, stream>>>(A, row_start, csr_rec, b1, B, flagp);
    // ---- layer 2 ----
    mgemm_kernel<64, 64, false><<<gm, 256, 0, stream>>>(B, W2, A, flagp);
    spmm_kernel<64, true, false><<<gs64, 256, 0, stream>>>(A, row_start, csr_rec, b2, B, flagp);
    // ---- layer 3 ----
    mgemm_kernel<64, 16, false><<<gm, 256, 0, stream>>>(B, W3, A, flagp);
    spmm_kernel<16, false, true><<<g64, 256, 0, stream>>>(A, row_start, csr_rec, b3, d_out, flagp);
}

// Round 9
// 266.017 us; speedup vs baseline: 1.6804x; 1.0425x over previous
//
#include <hip/hip_runtime.h>
#include <stdint.h>

#define N_NODES 100000
#define N_EDGES 1000000
#define NBUCK 98  // ceil(N_NODES / 1024)

typedef __attribute__((ext_vector_type(8))) __bf16 bf16x8;
typedef __attribute__((ext_vector_type(4))) float f32x4;

// ---------- bf16 helpers ----------
static __device__ __forceinline__ float bf2f(unsigned short u) {
    return __uint_as_float(((unsigned int)u) << 16);
}
static __device__ __forceinline__ unsigned short f2bf(float f) {
    unsigned int u = __float_as_uint(f);
    unsigned int r = (u + 0x7FFFu + ((u >> 16) & 1u)) >> 16;  // RNE
    return (unsigned short)r;
}
static __device__ __forceinline__ float4 ld4_half(const unsigned short* p) {
    ushort4 u = *(const ushort4*)p;
    return make_float4(bf2f(u.x), bf2f(u.y), bf2f(u.z), bf2f(u.w));
}
static __device__ __forceinline__ void st4_half(unsigned short* p, float4 f) {
    ushort4 u;
    u.x = f2bf(f.x); u.y = f2bf(f.y); u.z = f2bf(f.z); u.w = f2bf(f.w);
    *(ushort4*)p = u;
}

// ---------- dynamic-dtype external loads (flag: 1 = bf16 memory, 0 = f32) ----------
static __device__ __forceinline__ float ldf(const void* p, size_t i, int bf) {
    return bf ? bf2f(((const unsigned short*)p)[i]) : ((const float*)p)[i];
}
static __device__ __forceinline__ float4 ldf4(const void* p, size_t i, int bf) {
    if (bf) return ld4_half((const unsigned short*)p + i);
    return *(const float4*)((const float*)p + i);
}

// ---------- dtype probe ----------
__global__ __launch_bounds__(256) void detect_kernel(const unsigned short* __restrict__ xs,
                                                     int* __restrict__ flag) {
    __shared__ int sz;
    if (threadIdx.x == 0) sz = 0;
    __syncthreads();
    int z = 0;
    for (int i = threadIdx.x; i < 1024; i += 256) {
        float av = fabsf(bf2f(xs[2 * i]));
        if (!(av <= 1048576.0f) || (av != 0.0f && av < 9.5367431640625e-07f)) z++;
    }
    atomicAdd(&sz, z);
    __syncthreads();
    if (threadIdx.x == 0) *flag = (sz > 256) ? 0 : 1;
}

// ---------- CSR build, bucket-local ----------
__global__ __launch_bounds__(256) void bhist_kernel(const int* __restrict__ dst,
                                                    int* __restrict__ bcount) {
    __shared__ int cnt[NBUCK];
    int tid = threadIdx.x;
    for (int i = tid; i < NBUCK; i += 256) cnt[i] = 0;
    __syncthreads();
    int e0 = blockIdx.x * 4096;
#pragma unroll
    for (int i = 0; i < 16; ++i) {
        int e = e0 + i * 256 + tid;
        if (e < N_EDGES) atomicAdd(&cnt[dst[e] >> 10], 1);
    }
    __syncthreads();
    for (int i = tid; i < NBUCK; i += 256) {
        int c = cnt[i];
        if (c) atomicAdd(&bcount[i], c);
    }
}

__global__ __launch_bounds__(128) void bscan_kernel(const int* __restrict__ bcount,
                                                    int* __restrict__ bstart,
                                                    int* __restrict__ bcursor) {
    __shared__ int sh[128];
    int tid = threadIdx.x;
    int v = (tid < NBUCK) ? bcount[tid] : 0;
    sh[tid] = v;
    __syncthreads();
    for (int off = 1; off < 128; off <<= 1) {
        int t = 0;
        if (tid >= off) t = sh[tid - off];
        __syncthreads();
        if (tid >= off) sh[tid] += t;
        __syncthreads();
    }
    if (tid < NBUCK) {
        int excl = sh[tid] - v;
        bstart[tid] = excl;
        bcursor[tid] = excl;
    }
    if (tid == NBUCK - 1) bstart[NBUCK] = sh[tid];
}

__global__ __launch_bounds__(256) void part_kernel(const int* __restrict__ src,
                                                   const int* __restrict__ dst,
                                                   const void* __restrict__ val,
                                                   int* __restrict__ bcursor,
                                                   int2* __restrict__ part,
                                                   const int* __restrict__ flagp) {
    __shared__ int cnt[NBUCK];
    __shared__ int base[NBUCK];
    const int bf = *flagp;
    const int tid = threadIdx.x;
    const int e0 = blockIdx.x * 2048;
    for (int i = tid; i < NBUCK; i += 256) cnt[i] = 0;
    __syncthreads();
    int rank[8], bkt[8], pk[8], vb[8];
#pragma unroll
    for (int i = 0; i < 8; ++i) {
        int e = e0 + i * 256 + tid;
        bkt[i] = -1;
        if (e < N_EDGES) {
            int d = dst[e];
            int b = d >> 10;
            bkt[i] = b;
            pk[i] = src[e] | ((d & 1023) << 17);
            vb[i] = __float_as_int(ldf(val, e, bf));
            rank[i] = atomicAdd(&cnt[b], 1);
        }
    }
    __syncthreads();
    for (int i = tid; i < NBUCK; i += 256) {
        int c = cnt[i];
        base[i] = c ? atomicAdd(&bcursor[i], c) : 0;
    }
    __syncthreads();
#pragma unroll
    for (int i = 0; i < 8; ++i) {
        if (bkt[i] >= 0) part[(size_t)base[bkt[i]] + rank[i]] = make_int2(pk[i], vb[i]);
    }
}

__global__ __launch_bounds__(512) void place_kernel(const int* __restrict__ bstart,
                                                    const int2* __restrict__ part,
                                                    int* __restrict__ row_start,
                                                    int2* __restrict__ csr_rec) {
    __shared__ int cnt[1024];
    __shared__ int sums[512];
    const int tid = threadIdx.x;
    const int b = blockIdx.x;
    const int row0 = b << 10;
    const int nrows = min(1024, N_NODES - row0);
    const int s = bstart[b], e = bstart[b + 1];

    for (int i = tid; i < 1024; i += 512) cnt[i] = 0;
    __syncthreads();
    for (int j = s + tid; j < e; j += 512) {
        unsigned p = (unsigned)part[j].x;
        atomicAdd(&cnt[p >> 17], 1);
    }
    __syncthreads();
    int a0 = cnt[2 * tid], a1 = cnt[2 * tid + 1];
    int ts = a0 + a1;
    sums[tid] = ts;
    __syncthreads();
    for (int off = 1; off < 512; off <<= 1) {
        int t = 0;
        if (tid >= off) t = sums[tid - off];
        __syncthreads();
        if (tid >= off) sums[tid] += t;
        __syncthreads();
    }
    int excl = sums[tid] - ts;
    cnt[2 * tid] = s + excl;
    cnt[2 * tid + 1] = s + excl + a0;
    if (2 * tid < nrows)     row_start[row0 + 2 * tid] = s + excl;
    if (2 * tid + 1 < nrows) row_start[row0 + 2 * tid + 1] = s + excl + a0;
    if (b == NBUCK - 1 && tid == 0) row_start[N_NODES] = e;
    __syncthreads();
    for (int j = s + tid; j < e; j += 512) {
        int2 r = part[j];
        unsigned p = (unsigned)r.x;
        int pos = atomicAdd(&cnt[p >> 17], 1);
        csr_rec[pos] = make_int2((int)(p & 0x1FFFFu), r.y);
    }
}

// ---------- 8-wide-unrolled per-row gather accumulate (edge order preserved) ----------
static __device__ __forceinline__ void row_gather(const unsigned short* __restrict__ supc,
                                                  const int2* __restrict__ csr_rec,
                                                  int s, int e, int M,
                                                  float& a0, float& a1, float& a2, float& a3) {
    int j = s;
    for (; j + 7 < e; j += 8) {
        int2 r[8];
#pragma unroll
        for (int t = 0; t < 8; ++t) r[t] = csr_rec[j + t];
        float4 sp[8];
#pragma unroll
        for (int t = 0; t < 8; ++t) sp[t] = ld4_half(supc + (size_t)r[t].x * M);
#pragma unroll
        for (int t = 0; t < 8; ++t) {
            float v = __int_as_float(r[t].y);
            a0 += v * sp[t].x; a1 += v * sp[t].y; a2 += v * sp[t].z; a3 += v * sp[t].w;
        }
    }
    if (j + 3 < e) {
        int2 r[4];
#pragma unroll
        for (int t = 0; t < 4; ++t) r[t] = csr_rec[j + t];
        float4 sp[4];
#pragma unroll
        for (int t = 0; t < 4; ++t) sp[t] = ld4_half(supc + (size_t)r[t].x * M);
#pragma unroll
        for (int t = 0; t < 4; ++t) {
            float v = __int_as_float(r[t].y);
            a0 += v * sp[t].x; a1 += v * sp[t].y; a2 += v * sp[t].z; a3 += v * sp[t].w;
        }
        j += 4;
    }
    for (; j < e; ++j) {
        int2 rec = csr_rec[j];
        float v = __int_as_float(rec.y);
        float4 sp = ld4_half(supc + (size_t)rec.x * M);
        a0 += v * sp.x; a1 += v * sp.y; a2 += v * sp.z; a3 += v * sp.w;
    }
}

// ---------- MFMA GEMM (layer 1): A direct from global, B read from LDS ----------
template <int K, int M, bool DYNIN>
__global__ __launch_bounds__(256, 4) void mgemm_kernel(const void* __restrict__ hv_,
                                                       const void* __restrict__ W,
                                                       unsigned short* __restrict__ out,
                                                       const int* __restrict__ flagp) {
    constexpr int KP = K + 8;
    constexpr int NC = M / 16;
    constexpr int NK = K / 32;
    constexpr int NT = (N_NODES + 63) / 64;

    __shared__ unsigned short wt[M][KP];  // W transposed

    const int bf = *flagp;
    const int tid = threadIdx.x;

    for (int i = tid; i < K * M; i += 256) {
        int k = i / M, m = i % M;
        wt[m][k] = f2bf(ldf(W, i, bf));
    }
    __syncthreads();

    const int lane = tid & 63;
    const int qd = lane >> 4;
    const int ln = lane & 15;
    const int wrow = (tid >> 6) * 16;

    for (int tile = blockIdx.x; tile < NT; tile += gridDim.x) {
        const int row = tile * 64 + wrow + ln;
        const bool ok = row < N_NODES;

        f32x4 acc[NC];
#pragma unroll
        for (int c = 0; c < NC; ++c) acc[c] = (f32x4){0.f, 0.f, 0.f, 0.f};

#pragma unroll
        for (int ks = 0; ks < NK; ++ks) {
            bf16x8 a;
            if (ok) {
                const size_t base = (size_t)row * K + ks * 32 + qd * 8;
                if (DYNIN && !bf) {
                    const float* xp = (const float*)hv_ + base;
                    float4 f0 = *(const float4*)xp;
                    float4 f1 = *(const float4*)(xp + 4);
                    ushort4 uu[2];
                    uu[0].x = f2bf(f0.x); uu[0].y = f2bf(f0.y); uu[0].z = f2bf(f0.z); uu[0].w = f2bf(f0.w);
                    uu[1].x = f2bf(f1.x); uu[1].y = f2bf(f1.y); uu[1].z = f2bf(f1.z); uu[1].w = f2bf(f1.w);
                    a = *(const bf16x8*)uu;
                } else {
                    a = *(const bf16x8*)((const unsigned short*)hv_ + base);
                }
            } else {
                a = (bf16x8)(__bf16)0.0f;
            }
#pragma unroll
            for (int c = 0; c < NC; ++c) {
                bf16x8 b = *(const bf16x8*)&wt[c * 16 + ln][ks * 32 + qd * 8];
                acc[c] = __builtin_amdgcn_mfma_f32_16x16x32_bf16(a, b, acc[c], 0, 0, 0);
            }
        }

#pragma unroll
        for (int c = 0; c < NC; ++c) {
#pragma unroll
            for (int r = 0; r < 4; ++r) {
                int orow = tile * 64 + wrow + qd * 4 + r;
                if (orow < N_NODES) out[(size_t)orow * M + c * 16 + ln] = f2bf(acc[c][r]);
            }
        }
    }
}

// ---------- Fused: agg = relu(spmm(support)+bias); out = agg @ W  (K=64 fixed) ----------
// 64-row tiles; gather prologue -> LDS agg tile -> MFMA. Deletes the B round trip.
template <int MOUT>
__global__ __launch_bounds__(256, 4) void fused_kernel(const unsigned short* __restrict__ support,
                                                       const int* __restrict__ row_start,
                                                       const int2* __restrict__ csr_rec,
                                                       const void* __restrict__ bias,
                                                       const void* __restrict__ W,
                                                       unsigned short* __restrict__ out,
                                                       const int* __restrict__ flagp) {
    constexpr int K = 64, KP = 72;
    constexpr int NC = MOUT / 16;
    constexpr int NK = 2;
    constexpr int NT = (N_NODES + 63) / 64;

    __shared__ unsigned short agg[64][KP];
    __shared__ unsigned short wt[MOUT][KP];

    const int bf = *flagp;
    const int tid = threadIdx.x;

    for (int i = tid; i < K * MOUT; i += 256) {
        int k = i / MOUT, m = i % MOUT;
        wt[m][k] = f2bf(ldf(W, i, bf));
    }
    __syncthreads();

    const int lane = tid & 63;
    const int qd = lane >> 4;
    const int ln = lane & 15;
    const int wrow = (tid >> 6) * 16;

    // hoist B fragments (32 VGPRs for MOUT=64)
    bf16x8 bfrag[NK][NC];
#pragma unroll
    for (int ks = 0; ks < NK; ++ks)
#pragma unroll
        for (int c = 0; c < NC; ++c)
            bfrag[ks][c] = *(const bf16x8*)&wt[c * 16 + ln][ks * 32 + qd * 8];

    // gather-phase mapping: group g = tid>>4 handles rows g*4..g*4+3; lane c = tid&15 -> cols c*4..+3
    const int grp = tid >> 4;
    const int cc = tid & 15;
    const float bs0 = ldf(bias, cc * 4 + 0, bf);
    const float bs1 = ldf(bias, cc * 4 + 1, bf);
    const float bs2 = ldf(bias, cc * 4 + 2, bf);
    const float bs3 = ldf(bias, cc * 4 + 3, bf);
    const unsigned short* supc = support + cc * 4;

    for (int tile = blockIdx.x; tile < NT; tile += gridDim.x) {
#pragma unroll
        for (int rr = 0; rr < 4; ++rr) {
            int rl = grp * 4 + rr;
            int row = tile * 64 + rl;
            float a0 = bs0, a1 = bs1, a2 = bs2, a3 = bs3;
            if (row < N_NODES) {
                int s = row_start[row];
                int e = row_start[row + 1];
                row_gather(supc, csr_rec, s, e, 64, a0, a1, a2, a3);
                a0 = fmaxf(a0, 0.f); a1 = fmaxf(a1, 0.f);
                a2 = fmaxf(a2, 0.f); a3 = fmaxf(a3, 0.f);
            } else {
                a0 = a1 = a2 = a3 = 0.f;
            }
            st4_half(&agg[rl][cc * 4], make_float4(a0, a1, a2, a3));
        }
        __syncthreads();

        f32x4 acc[NC];
#pragma unroll
        for (int c = 0; c < NC; ++c) acc[c] = (f32x4){0.f, 0.f, 0.f, 0.f};
#pragma unroll
        for (int ks = 0; ks < NK; ++ks) {
            bf16x8 a = *(const bf16x8*)&agg[wrow + ln][ks * 32 + qd * 8];
#pragma unroll
            for (int c = 0; c < NC; ++c)
                acc[c] = __builtin_amdgcn_mfma_f32_16x16x32_bf16(a, bfrag[ks][c], acc[c], 0, 0, 0);
        }

#pragma unroll
        for (int c = 0; c < NC; ++c) {
#pragma unroll
            for (int r = 0; r < 4; ++r) {
                int orow = tile * 64 + wrow + qd * 4 + r;
                if (orow < N_NODES) out[(size_t)orow * MOUT + c * 16 + ln] = f2bf(acc[c][r]);
            }
        }
        __syncthreads();  // agg reused next tile
    }
}

// ---------- final SpMM (M=16), 8-wide unrolled ----------
template <bool DYNOUT>
__global__ __launch_bounds__(256) void spmm16_kernel(const unsigned short* __restrict__ support,
                                                     const int* __restrict__ row_start,
                                                     const int2* __restrict__ csr_rec,
                                                     const void* __restrict__ bias,
                                                     void* __restrict__ out_,
                                                     const int* __restrict__ flagp) {
    constexpr int M = 16;
    int bf = *flagp;
    int tid = threadIdx.x;
    int gid = blockIdx.x * 64 + tid / 4;
    int c0 = (tid % 4) * 4;
    if (gid >= N_NODES) return;
    int s = row_start[gid];
    int e = row_start[gid + 1];
    float a0 = ldf(bias, c0 + 0, bf);
    float a1 = ldf(bias, c0 + 1, bf);
    float a2 = ldf(bias, c0 + 2, bf);
    float a3 = ldf(bias, c0 + 3, bf);
    row_gather(support + c0, csr_rec, s, e, M, a0, a1, a2, a3);
    float4 f = make_float4(a0, a1, a2, a3);
    if (DYNOUT && !bf) *(float4*)((float*)out_ + (size_t)gid * M + c0) = f;
    else               st4_half((unsigned short*)out_ + (size_t)gid * M + c0, f);
}

extern "C" void kernel_launch(void* const* d_in, const int* in_sizes, int n_in,
                              void* d_out, int out_size, void* d_ws, size_t ws_size,
                              hipStream_t stream) {
    (void)in_sizes; (void)n_in; (void)out_size; (void)ws_size;
    const void* x  = d_in[0];
    const void* ev = d_in[1];
    const void* W1 = d_in[2];
    const void* b1 = d_in[3];
    const void* W2 = d_in[4];
    const void* b2 = d_in[5];
    const void* W3 = d_in[6];
    const void* b3 = d_in[7];
    const int* esrc = (const int*)d_in[8];
    const int* edst = (const int*)d_in[9];

    // workspace (~34 MB)
    char* ws = (char*)d_ws;
    size_t off = 0;
    auto alloc = [&](size_t bytes) -> void* {
        void* p = ws + off;
        off = (off + bytes + 255) & ~(size_t)255;
        return p;
    };
    unsigned short* A = (unsigned short*)alloc((size_t)N_NODES * 64 * 2);  // support1 / A3
    unsigned short* B = (unsigned short*)alloc((size_t)N_NODES * 64 * 2);  // A2
    int* row_start  = (int*)alloc((size_t)(N_NODES + 1) * 4);
    int* bcount     = (int*)alloc(512);
    int* bstart     = (int*)alloc(512);
    int* bcursor    = (int*)alloc(512);
    int2* csr_rec   = (int2*)alloc((size_t)N_EDGES * 8);
    int* flagp      = (int*)alloc(256);
    // part[] (8 MB) aliases A (12.8 MB): dead before mgemm1 writes A
    int2* part      = (int2*)A;

    // ---- dtype probe ----
    detect_kernel<<<1, 256, 0, stream>>>((const unsigned short*)x, flagp);

    // ---- bucket-local CSR build ----
    hipMemsetAsync(bcount, 0, 512, stream);
    bhist_kernel<<<(N_EDGES + 4095) / 4096, 256, 0, stream>>>(edst, bcount);
    bscan_kernel<<<1, 128, 0, stream>>>(bcount, bstart, bcursor);
    part_kernel<<<(N_EDGES + 2047) / 2048, 256, 0, stream>>>(esrc, edst, ev, bcursor, part, flagp);
    place_kernel<<<NBUCK, 512, 0, stream>>>(bstart, part, row_start, csr_rec);

    // ---- layer 1: A = x @ W1 ----
    mgemm_kernel<128, 64, true><<<1024, 256, 0, stream>>>(x, W1, A, flagp);
    // ---- layer 1 agg + layer 2 gemm fused: B = relu(spmm(A)+b1) @ W2 ----
    fused_kernel<64><<<1024, 256, 0, stream>>>(A, row_start, csr_rec, b1, W2, B, flagp);
    // ---- layer 2 agg + layer 3 gemm fused: A(=A3) = relu(spmm(B)+b2) @ W3 ----
    fused_kernel<16><<<1024, 256, 0, stream>>>(B, row_start, csr_rec, b2, W3, A, flagp);
    // ---- final aggregation: out = spmm(A3) + b3 ----
    spmm16_kernel<true><<<(N_NODES + 63) / 64, 256, 0, stream>>>(A, row_start, csr_rec, b3, d_out, flagp);
}

// Round 10
// 261.982 us; speedup vs baseline: 1.7063x; 1.0154x over previous
//
#include <hip/hip_runtime.h>
#include <stdint.h>

#define N_NODES 100000
#define N_EDGES 1000000
#define NBUCK 98  // ceil(N_NODES / 1024)

typedef __attribute__((ext_vector_type(8))) __bf16 bf16x8;
typedef __attribute__((ext_vector_type(4))) float f32x4;

// ---------- bf16 helpers ----------
static __device__ __forceinline__ float bf2f(unsigned short u) {
    return __uint_as_float(((unsigned int)u) << 16);
}
static __device__ __forceinline__ unsigned short f2bf(float f) {
    unsigned int u = __float_as_uint(f);
    unsigned int r = (u + 0x7FFFu + ((u >> 16) & 1u)) >> 16;  // RNE
    return (unsigned short)r;
}
static __device__ __forceinline__ float4 ld4_half(const unsigned short* p) {
    ushort4 u = *(const ushort4*)p;
    return make_float4(bf2f(u.x), bf2f(u.y), bf2f(u.z), bf2f(u.w));
}
static __device__ __forceinline__ void st4_half(unsigned short* p, float4 f) {
    ushort4 u;
    u.x = f2bf(f.x); u.y = f2bf(f.y); u.z = f2bf(f.z); u.w = f2bf(f.w);
    *(ushort4*)p = u;
}

// ---------- dynamic-dtype external loads (flag: 1 = bf16 memory, 0 = f32) ----------
static __device__ __forceinline__ float ldf(const void* p, size_t i, int bf) {
    return bf ? bf2f(((const unsigned short*)p)[i]) : ((const float*)p)[i];
}
static __device__ __forceinline__ float4 ldf4(const void* p, size_t i, int bf) {
    if (bf) return ld4_half((const unsigned short*)p + i);
    return *(const float4*)((const float*)p + i);
}

// ---------- dtype probe ----------
__global__ __launch_bounds__(256) void detect_kernel(const unsigned short* __restrict__ xs,
                                                     int* __restrict__ flag) {
    __shared__ int sz;
    if (threadIdx.x == 0) sz = 0;
    __syncthreads();
    int z = 0;
    for (int i = threadIdx.x; i < 1024; i += 256) {
        float av = fabsf(bf2f(xs[2 * i]));
        if (!(av <= 1048576.0f) || (av != 0.0f && av < 9.5367431640625e-07f)) z++;
    }
    atomicAdd(&sz, z);
    __syncthreads();
    if (threadIdx.x == 0) *flag = (sz > 256) ? 0 : 1;
}

// ---------- CSR build, bucket-local ----------
__global__ __launch_bounds__(256) void bhist_kernel(const int* __restrict__ dst,
                                                    int* __restrict__ bcount) {
    __shared__ int cnt[NBUCK];
    int tid = threadIdx.x;
    for (int i = tid; i < NBUCK; i += 256) cnt[i] = 0;
    __syncthreads();
    int e0 = blockIdx.x * 4096;
#pragma unroll
    for (int i = 0; i < 16; ++i) {
        int e = e0 + i * 256 + tid;
        if (e < N_EDGES) atomicAdd(&cnt[dst[e] >> 10], 1);
    }
    __syncthreads();
    for (int i = tid; i < NBUCK; i += 256) {
        int c = cnt[i];
        if (c) atomicAdd(&bcount[i], c);
    }
}

__global__ __launch_bounds__(128) void bscan_kernel(const int* __restrict__ bcount,
                                                    int* __restrict__ bstart,
                                                    int* __restrict__ bcursor) {
    __shared__ int sh[128];
    int tid = threadIdx.x;
    int v = (tid < NBUCK) ? bcount[tid] : 0;
    sh[tid] = v;
    __syncthreads();
    for (int off = 1; off < 128; off <<= 1) {
        int t = 0;
        if (tid >= off) t = sh[tid - off];
        __syncthreads();
        if (tid >= off) sh[tid] += t;
        __syncthreads();
    }
    if (tid < NBUCK) {
        int excl = sh[tid] - v;
        bstart[tid] = excl;
        bcursor[tid] = excl;
    }
    if (tid == NBUCK - 1) bstart[NBUCK] = sh[tid];
}

__global__ __launch_bounds__(256) void part_kernel(const int* __restrict__ src,
                                                   const int* __restrict__ dst,
                                                   const void* __restrict__ val,
                                                   int* __restrict__ bcursor,
                                                   int2* __restrict__ part,
                                                   const int* __restrict__ flagp) {
    __shared__ int cnt[NBUCK];
    __shared__ int base[NBUCK];
    const int bf = *flagp;
    const int tid = threadIdx.x;
    const int e0 = blockIdx.x * 2048;
    for (int i = tid; i < NBUCK; i += 256) cnt[i] = 0;
    __syncthreads();
    int rank[8], bkt[8], pk[8], vb[8];
#pragma unroll
    for (int i = 0; i < 8; ++i) {
        int e = e0 + i * 256 + tid;
        bkt[i] = -1;
        if (e < N_EDGES) {
            int d = dst[e];
            int b = d >> 10;
            bkt[i] = b;
            pk[i] = src[e] | ((d & 1023) << 17);
            vb[i] = __float_as_int(ldf(val, e, bf));
            rank[i] = atomicAdd(&cnt[b], 1);
        }
    }
    __syncthreads();
    for (int i = tid; i < NBUCK; i += 256) {
        int c = cnt[i];
        base[i] = c ? atomicAdd(&bcursor[i], c) : 0;
    }
    __syncthreads();
#pragma unroll
    for (int i = 0; i < 8; ++i) {
        if (bkt[i] >= 0) part[(size_t)base[bkt[i]] + rank[i]] = make_int2(pk[i], vb[i]);
    }
}

__global__ __launch_bounds__(512) void place_kernel(const int* __restrict__ bstart,
                                                    const int2* __restrict__ part,
                                                    int* __restrict__ row_start,
                                                    int2* __restrict__ csr_rec) {
    __shared__ int cnt[1024];
    __shared__ int sums[512];
    const int tid = threadIdx.x;
    const int b = blockIdx.x;
    const int row0 = b << 10;
    const int nrows = min(1024, N_NODES - row0);
    const int s = bstart[b], e = bstart[b + 1];

    for (int i = tid; i < 1024; i += 512) cnt[i] = 0;
    __syncthreads();
    for (int j = s + tid; j < e; j += 512) {
        unsigned p = (unsigned)part[j].x;
        atomicAdd(&cnt[p >> 17], 1);
    }
    __syncthreads();
    int a0 = cnt[2 * tid], a1 = cnt[2 * tid + 1];
    int ts = a0 + a1;
    sums[tid] = ts;
    __syncthreads();
    for (int off = 1; off < 512; off <<= 1) {
        int t = 0;
        if (tid >= off) t = sums[tid - off];
        __syncthreads();
        if (tid >= off) sums[tid] += t;
        __syncthreads();
    }
    int excl = sums[tid] - ts;
    cnt[2 * tid] = s + excl;
    cnt[2 * tid + 1] = s + excl + a0;
    if (2 * tid < nrows)     row_start[row0 + 2 * tid] = s + excl;
    if (2 * tid + 1 < nrows) row_start[row0 + 2 * tid + 1] = s + excl + a0;
    if (b == NBUCK - 1 && tid == 0) row_start[N_NODES] = e;
    __syncthreads();
    for (int j = s + tid; j < e; j += 512) {
        int2 r = part[j];
        unsigned p = (unsigned)r.x;
        int pos = atomicAdd(&cnt[p >> 17], 1);
        csr_rec[pos] = make_int2((int)(p & 0x1FFFFu), r.y);
    }
}

// ---------- uniform predicated gather: clamped 8-wide batches, pipelined recs ----------
// No scalar tail: slot t of batch at j reads rec[min(j+t, e-1)]; weight 0 if j+t >= e.
// Next batch's recs are prefetched while this batch's gathers are in flight.
static __device__ __forceinline__ void row_gather_u(const unsigned short* __restrict__ supc,
                                                    const int2* __restrict__ csr_rec,
                                                    int s, int e, int M,
                                                    float& a0, float& a1, float& a2, float& a3) {
    if (s >= e) return;
    int2 r[8];
#pragma unroll
    for (int t = 0; t < 8; ++t) r[t] = csr_rec[min(s + t, e - 1)];
    for (int j = s; j < e; j += 8) {
        float4 sp[8];
#pragma unroll
        for (int t = 0; t < 8; ++t) sp[t] = ld4_half(supc + (size_t)r[t].x * M);
        float v[8];
#pragma unroll
        for (int t = 0; t < 8; ++t) v[t] = (j + t < e) ? __int_as_float(r[t].y) : 0.0f;
        int jn = j + 8;
        if (jn < e) {
#pragma unroll
            for (int t = 0; t < 8; ++t) r[t] = csr_rec[min(jn + t, e - 1)];
        }
#pragma unroll
        for (int t = 0; t < 8; ++t) {
            a0 += v[t] * sp[t].x; a1 += v[t] * sp[t].y;
            a2 += v[t] * sp[t].z; a3 += v[t] * sp[t].w;
        }
    }
}

// ---------- MFMA GEMM (layer 1): A direct from global, B read from LDS ----------
template <int K, int M, bool DYNIN>
__global__ __launch_bounds__(256, 4) void mgemm_kernel(const void* __restrict__ hv_,
                                                       const void* __restrict__ W,
                                                       unsigned short* __restrict__ out,
                                                       const int* __restrict__ flagp) {
    constexpr int KP = K + 8;
    constexpr int NC = M / 16;
    constexpr int NK = K / 32;
    constexpr int NT = (N_NODES + 63) / 64;

    __shared__ unsigned short wt[M][KP];  // W transposed

    const int bf = *flagp;
    const int tid = threadIdx.x;

    for (int i = tid; i < K * M; i += 256) {
        int k = i / M, m = i % M;
        wt[m][k] = f2bf(ldf(W, i, bf));
    }
    __syncthreads();

    const int lane = tid & 63;
    const int qd = lane >> 4;
    const int ln = lane & 15;
    const int wrow = (tid >> 6) * 16;

    for (int tile = blockIdx.x; tile < NT; tile += gridDim.x) {
        const int row = tile * 64 + wrow + ln;
        const bool ok = row < N_NODES;

        f32x4 acc[NC];
#pragma unroll
        for (int c = 0; c < NC; ++c) acc[c] = (f32x4){0.f, 0.f, 0.f, 0.f};

#pragma unroll
        for (int ks = 0; ks < NK; ++ks) {
            bf16x8 a;
            if (ok) {
                const size_t base = (size_t)row * K + ks * 32 + qd * 8;
                if (DYNIN && !bf) {
                    const float* xp = (const float*)hv_ + base;
                    float4 f0 = *(const float4*)xp;
                    float4 f1 = *(const float4*)(xp + 4);
                    ushort4 uu[2];
                    uu[0].x = f2bf(f0.x); uu[0].y = f2bf(f0.y); uu[0].z = f2bf(f0.z); uu[0].w = f2bf(f0.w);
                    uu[1].x = f2bf(f1.x); uu[1].y = f2bf(f1.y); uu[1].z = f2bf(f1.z); uu[1].w = f2bf(f1.w);
                    a = *(const bf16x8*)uu;
                } else {
                    a = *(const bf16x8*)((const unsigned short*)hv_ + base);
                }
            } else {
                a = (bf16x8)(__bf16)0.0f;
            }
#pragma unroll
            for (int c = 0; c < NC; ++c) {
                bf16x8 b = *(const bf16x8*)&wt[c * 16 + ln][ks * 32 + qd * 8];
                acc[c] = __builtin_amdgcn_mfma_f32_16x16x32_bf16(a, b, acc[c], 0, 0, 0);
            }
        }

#pragma unroll
        for (int c = 0; c < NC; ++c) {
#pragma unroll
            for (int r = 0; r < 4; ++r) {
                int orow = tile * 64 + wrow + qd * 4 + r;
                if (orow < N_NODES) out[(size_t)orow * M + c * 16 + ln] = f2bf(acc[c][r]);
            }
        }
    }
}

// ---------- Fused: agg = relu(spmm(support)+bias); out = agg @ W  (K=64 fixed) ----------
template <int MOUT>
__global__ __launch_bounds__(256, 4) void fused_kernel(const unsigned short* __restrict__ support,
                                                       const int* __restrict__ row_start,
                                                       const int2* __restrict__ csr_rec,
                                                       const void* __restrict__ bias,
                                                       const void* __restrict__ W,
                                                       unsigned short* __restrict__ out,
                                                       const int* __restrict__ flagp) {
    constexpr int K = 64, KP = 72;
    constexpr int NC = MOUT / 16;
    constexpr int NK = 2;
    constexpr int NT = (N_NODES + 63) / 64;

    __shared__ unsigned short agg[64][KP];
    __shared__ unsigned short wt[MOUT][KP];

    const int bf = *flagp;
    const int tid = threadIdx.x;

    for (int i = tid; i < K * MOUT; i += 256) {
        int k = i / MOUT, m = i % MOUT;
        wt[m][k] = f2bf(ldf(W, i, bf));
    }
    __syncthreads();

    const int lane = tid & 63;
    const int qd = lane >> 4;
    const int ln = lane & 15;
    const int wrow = (tid >> 6) * 16;

    // gather-phase mapping: group g = tid>>4 handles rows g*4..g*4+3; lane c = tid&15 -> cols c*4..+3
    const int grp = tid >> 4;
    const int cc = tid & 15;
    const float bs0 = ldf(bias, cc * 4 + 0, bf);
    const float bs1 = ldf(bias, cc * 4 + 1, bf);
    const float bs2 = ldf(bias, cc * 4 + 2, bf);
    const float bs3 = ldf(bias, cc * 4 + 3, bf);
    const unsigned short* supc = support + cc * 4;

    for (int tile = blockIdx.x; tile < NT; tile += gridDim.x) {
#pragma unroll
        for (int rr = 0; rr < 4; ++rr) {
            int rl = grp * 4 + rr;
            int row = tile * 64 + rl;
            float a0 = bs0, a1 = bs1, a2 = bs2, a3 = bs3;
            if (row < N_NODES) {
                int s = row_start[row];
                int e = row_start[row + 1];
                row_gather_u(supc, csr_rec, s, e, 64, a0, a1, a2, a3);
                a0 = fmaxf(a0, 0.f); a1 = fmaxf(a1, 0.f);
                a2 = fmaxf(a2, 0.f); a3 = fmaxf(a3, 0.f);
            } else {
                a0 = a1 = a2 = a3 = 0.f;
            }
            st4_half(&agg[rl][cc * 4], make_float4(a0, a1, a2, a3));
        }
        __syncthreads();

        f32x4 acc[NC];
#pragma unroll
        for (int c = 0; c < NC; ++c) acc[c] = (f32x4){0.f, 0.f, 0.f, 0.f};
#pragma unroll
        for (int ks = 0; ks < NK; ++ks) {
            bf16x8 a = *(const bf16x8*)&agg[wrow + ln][ks * 32 + qd * 8];
#pragma unroll
            for (int c = 0; c < NC; ++c) {
                bf16x8 b = *(const bf16x8*)&wt[c * 16 + ln][ks * 32 + qd * 8];
                acc[c] = __builtin_amdgcn_mfma_f32_16x16x32_bf16(a, b, acc[c], 0, 0, 0);
            }
        }

#pragma unroll
        for (int c = 0; c < NC; ++c) {
#pragma unroll
            for (int r = 0; r < 4; ++r) {
                int orow = tile * 64 + wrow + qd * 4 + r;
                if (orow < N_NODES) out[(size_t)orow * MOUT + c * 16 + ln] = f2bf(acc[c][r]);
            }
        }
        __syncthreads();  // agg reused next tile
    }
}

// ---------- final SpMM (M=16), uniform pipelined gather ----------
template <bool DYNOUT>
__global__ __launch_bounds__(256) void spmm16_kernel(const unsigned short* __restrict__ support,
                                                     const int* __restrict__ row_start,
                                                     const int2* __restrict__ csr_rec,
                                                     const void* __restrict__ bias,
                                                     void* __restrict__ out_,
                                                     const int* __restrict__ flagp) {
    constexpr int M = 16;
    int bf = *flagp;
    int tid = threadIdx.x;
    int gid = blockIdx.x * 64 + tid / 4;
    int c0 = (tid % 4) * 4;
    if (gid >= N_NODES) return;
    int s = row_start[gid];
    int e = row_start[gid + 1];
    float a0 = ldf(bias, c0 + 0, bf);
    float a1 = ldf(bias, c0 + 1, bf);
    float a2 = ldf(bias, c0 + 2, bf);
    float a3 = ldf(bias, c0 + 3, bf);
    row_gather_u(support + c0, csr_rec, s, e, M, a0, a1, a2, a3);
    float4 f = make_float4(a0, a1, a2, a3);
    if (DYNOUT && !bf) *(float4*)((float*)out_ + (size_t)gid * M + c0) = f;
    else               st4_half((unsigned short*)out_ + (size_t)gid * M + c0, f);
}

extern "C" void kernel_launch(void* const* d_in, const int* in_sizes, int n_in,
                              void* d_out, int out_size, void* d_ws, size_t ws_size,
                              hipStream_t stream) {
    (void)in_sizes; (void)n_in; (void)out_size; (void)ws_size;
    const void* x  = d_in[0];
    const void* ev = d_in[1];
    const void* W1 = d_in[2];
    const void* b1 = d_in[3];
    const void* W2 = d_in[4];
    const void* b2 = d_in[5];
    const void* W3 = d_in[6];
    const void* b3 = d_in[7];
    const int* esrc = (const int*)d_in[8];
    const int* edst = (const int*)d_in[9];

    // workspace (~34 MB)
    char* ws = (char*)d_ws;
    size_t off = 0;
    auto alloc = [&](size_t bytes) -> void* {
        void* p = ws + off;
        off = (off + bytes + 255) & ~(size_t)255;
        return p;
    };
    unsigned short* A = (unsigned short*)alloc((size_t)N_NODES * 64 * 2);  // support1 / A3
    unsigned short* B = (unsigned short*)alloc((size_t)N_NODES * 64 * 2);  // A2
    int* row_start  = (int*)alloc((size_t)(N_NODES + 1) * 4);
    int* bcount     = (int*)alloc(512);
    int* bstart     = (int*)alloc(512);
    int* bcursor    = (int*)alloc(512);
    int2* csr_rec   = (int2*)alloc((size_t)N_EDGES * 8);
    int* flagp      = (int*)alloc(256);
    // part[] (8 MB) aliases A (12.8 MB): dead before mgemm1 writes A
    int2* part      = (int2*)A;

    // ---- dtype probe ----
    detect_kernel<<<1, 256, 0, stream>>>((const unsigned short*)x, flagp);

    // ---- bucket-local CSR build ----
    hipMemsetAsync(bcount, 0, 512, stream);
    bhist_kernel<<<(N_EDGES + 4095) / 4096, 256, 0, stream>>>(edst, bcount);
    bscan_kernel<<<1, 128, 0, stream>>>(bcount, bstart, bcursor);
    part_kernel<<<(N_EDGES + 2047) / 2048, 256, 0, stream>>>(esrc, edst, ev, bcursor, part, flagp);
    place_kernel<<<NBUCK, 512, 0, stream>>>(bstart, part, row_start, csr_rec);

    // ---- layer 1: A = x @ W1 ----
    mgemm_kernel<128, 64, true><<<1024, 256, 0, stream>>>(x, W1, A, flagp);
    // ---- layer 1 agg + layer 2 gemm fused: B = relu(spmm(A)+b1) @ W2 ----
    fused_kernel<64><<<1024, 256, 0, stream>>>(A, row_start, csr_rec, b1, W2, B, flagp);
    // ---- layer 2 agg + layer 3 gemm fused: A(=A3) = relu(spmm(B)+b2) @ W3 ----
    fused_kernel<16><<<1024, 256, 0, stream>>>(B, row_start, csr_rec, b2, W3, A, flagp);
    // ---- final aggregation: out = spmm(A3) + b3 ----
    spmm16_kernel<true><<<(N_NODES + 63) / 64, 256, 0, stream>>>(A, row_start, csr_rec, b3, d_out, flagp);
}

// Round 11
// 258.726 us; speedup vs baseline: 1.7277x; 1.0126x over previous
//
#include <hip/hip_runtime.h>
#include <stdint.h>

#define N_NODES 100000
#define N_EDGES 1000000
#define NBUCK 98  // ceil(N_NODES / 1024)

typedef __attribute__((ext_vector_type(8))) __bf16 bf16x8;
typedef __attribute__((ext_vector_type(4))) float f32x4;

// ---------- bf16 helpers ----------
static __device__ __forceinline__ float bf2f(unsigned short u) {
    return __uint_as_float(((unsigned int)u) << 16);
}
static __device__ __forceinline__ unsigned short f2bf(float f) {
    unsigned int u = __float_as_uint(f);
    unsigned int r = (u + 0x7FFFu + ((u >> 16) & 1u)) >> 16;  // RNE
    return (unsigned short)r;
}
static __device__ __forceinline__ float4 ld4_half(const unsigned short* p) {
    ushort4 u = *(const ushort4*)p;
    return make_float4(bf2f(u.x), bf2f(u.y), bf2f(u.z), bf2f(u.w));
}
static __device__ __forceinline__ void st4_half(unsigned short* p, float4 f) {
    ushort4 u;
    u.x = f2bf(f.x); u.y = f2bf(f.y); u.z = f2bf(f.z); u.w = f2bf(f.w);
    *(ushort4*)p = u;
}

// ---------- dynamic-dtype external loads (flag: 1 = bf16 memory, 0 = f32) ----------
static __device__ __forceinline__ float ldf(const void* p, size_t i, int bf) {
    return bf ? bf2f(((const unsigned short*)p)[i]) : ((const float*)p)[i];
}
static __device__ __forceinline__ float4 ldf4(const void* p, size_t i, int bf) {
    if (bf) return ld4_half((const unsigned short*)p + i);
    return *(const float4*)((const float*)p + i);
}

// ---------- dtype probe ----------
__global__ __launch_bounds__(256) void detect_kernel(const unsigned short* __restrict__ xs,
                                                     int* __restrict__ flag) {
    __shared__ int sz;
    if (threadIdx.x == 0) sz = 0;
    __syncthreads();
    int z = 0;
    for (int i = threadIdx.x; i < 1024; i += 256) {
        float av = fabsf(bf2f(xs[2 * i]));
        if (!(av <= 1048576.0f) || (av != 0.0f && av < 9.5367431640625e-07f)) z++;
    }
    atomicAdd(&sz, z);
    __syncthreads();
    if (threadIdx.x == 0) *flag = (sz > 256) ? 0 : 1;
}

// ---------- CSR build, bucket-local ----------
__global__ __launch_bounds__(256) void bhist_kernel(const int* __restrict__ dst,
                                                    int* __restrict__ bcount) {
    __shared__ int cnt[NBUCK];
    int tid = threadIdx.x;
    for (int i = tid; i < NBUCK; i += 256) cnt[i] = 0;
    __syncthreads();
    int e0 = blockIdx.x * 4096;
#pragma unroll
    for (int i = 0; i < 16; ++i) {
        int e = e0 + i * 256 + tid;
        if (e < N_EDGES) atomicAdd(&cnt[dst[e] >> 10], 1);
    }
    __syncthreads();
    for (int i = tid; i < NBUCK; i += 256) {
        int c = cnt[i];
        if (c) atomicAdd(&bcount[i], c);
    }
}

__global__ __launch_bounds__(128) void bscan_kernel(const int* __restrict__ bcount,
                                                    int* __restrict__ bstart,
                                                    int* __restrict__ bcursor) {
    __shared__ int sh[128];
    int tid = threadIdx.x;
    int v = (tid < NBUCK) ? bcount[tid] : 0;
    sh[tid] = v;
    __syncthreads();
    for (int off = 1; off < 128; off <<= 1) {
        int t = 0;
        if (tid >= off) t = sh[tid - off];
        __syncthreads();
        if (tid >= off) sh[tid] += t;
        __syncthreads();
    }
    if (tid < NBUCK) {
        int excl = sh[tid] - v;
        bstart[tid] = excl;
        bcursor[tid] = excl;
    }
    if (tid == NBUCK - 1) bstart[NBUCK] = sh[tid];
}

__global__ __launch_bounds__(256) void part_kernel(const int* __restrict__ src,
                                                   const int* __restrict__ dst,
                                                   const void* __restrict__ val,
                                                   int* __restrict__ bcursor,
                                                   int2* __restrict__ part,
                                                   const int* __restrict__ flagp) {
    __shared__ int cnt[NBUCK];
    __shared__ int base[NBUCK];
    const int bf = *flagp;
    const int tid = threadIdx.x;
    const int e0 = blockIdx.x * 2048;
    for (int i = tid; i < NBUCK; i += 256) cnt[i] = 0;
    __syncthreads();
    int rank[8], bkt[8], pk[8], vb[8];
#pragma unroll
    for (int i = 0; i < 8; ++i) {
        int e = e0 + i * 256 + tid;
        bkt[i] = -1;
        if (e < N_EDGES) {
            int d = dst[e];
            int b = d >> 10;
            bkt[i] = b;
            pk[i] = src[e] | ((d & 1023) << 17);
            vb[i] = __float_as_int(ldf(val, e, bf));
            rank[i] = atomicAdd(&cnt[b], 1);
        }
    }
    __syncthreads();
    for (int i = tid; i < NBUCK; i += 256) {
        int c = cnt[i];
        base[i] = c ? atomicAdd(&bcursor[i], c) : 0;
    }
    __syncthreads();
#pragma unroll
    for (int i = 0; i < 8; ++i) {
        if (bkt[i] >= 0) part[(size_t)base[bkt[i]] + rank[i]] = make_int2(pk[i], vb[i]);
    }
}

__global__ __launch_bounds__(512) void place_kernel(const int* __restrict__ bstart,
                                                    const int2* __restrict__ part,
                                                    int* __restrict__ row_start,
                                                    int2* __restrict__ csr_rec) {
    __shared__ int cnt[1024];
    __shared__ int sums[512];
    const int tid = threadIdx.x;
    const int b = blockIdx.x;
    const int row0 = b << 10;
    const int nrows = min(1024, N_NODES - row0);
    const int s = bstart[b], e = bstart[b + 1];

    for (int i = tid; i < 1024; i += 512) cnt[i] = 0;
    __syncthreads();
    for (int j = s + tid; j < e; j += 512) {
        unsigned p = (unsigned)part[j].x;
        atomicAdd(&cnt[p >> 17], 1);
    }
    __syncthreads();
    int a0 = cnt[2 * tid], a1 = cnt[2 * tid + 1];
    int ts = a0 + a1;
    sums[tid] = ts;
    __syncthreads();
    for (int off = 1; off < 512; off <<= 1) {
        int t = 0;
        if (tid >= off) t = sums[tid - off];
        __syncthreads();
        if (tid >= off) sums[tid] += t;
        __syncthreads();
    }
    int excl = sums[tid] - ts;
    cnt[2 * tid] = s + excl;
    cnt[2 * tid + 1] = s + excl + a0;
    if (2 * tid < nrows)     row_start[row0 + 2 * tid] = s + excl;
    if (2 * tid + 1 < nrows) row_start[row0 + 2 * tid + 1] = s + excl + a0;
    if (b == NBUCK - 1 && tid == 0) row_start[N_NODES] = e;
    __syncthreads();
    for (int j = s + tid; j < e; j += 512) {
        int2 r = part[j];
        unsigned p = (unsigned)r.x;
        int pos = atomicAdd(&cnt[p >> 17], 1);
        csr_rec[pos] = make_int2((int)(p & 0x1FFFFu), r.y);
    }
}

// ---------- flat-stream quad-row gather ----------
// One lane group handles 4 CONSECUTIVE dst rows whose edges form one contiguous
// range [s, e) in csr_rec. 8-wide pipelined batches over the whole range; each
// edge is routed to its row's accumulator via cumulative select masks.
// Masked terms are exactly +0.0f; per-row accumulation order is unchanged
// -> bit-identical to the per-row sequential version.
template <int M>
static __device__ __forceinline__ void quad_gather(const unsigned short* __restrict__ supc,
                                                   const int2* __restrict__ csr_rec,
                                                   int s, int b1, int b2, int b3, int e,
                                                   float4 acc[4]) {
    if (s >= e) return;
    int2 r[8];
#pragma unroll
    for (int t = 0; t < 8; ++t) r[t] = csr_rec[min(s + t, e - 1)];
    for (int j = s; j < e; j += 8) {
        float4 sp[8];
#pragma unroll
        for (int t = 0; t < 8; ++t) sp[t] = ld4_half(supc + (size_t)r[t].x * M);
        float wv[8];
#pragma unroll
        for (int t = 0; t < 8; ++t) wv[t] = (j + t < e) ? __int_as_float(r[t].y) : 0.0f;
        int jn = j + 8;
        if (jn < e) {
#pragma unroll
            for (int t = 0; t < 8; ++t) r[t] = csr_rec[min(jn + t, e - 1)];
        }
#pragma unroll
        for (int t = 0; t < 8; ++t) {
            int idx = j + t;
            float c0 = (idx < b1) ? wv[t] : 0.0f;   // cumulative masks
            float c1 = (idx < b2) ? wv[t] : 0.0f;
            float c2 = (idx < b3) ? wv[t] : 0.0f;
            float w0 = c0;
            float w1 = c1 - c0;   // exact: wv-wv=0 or wv-0=wv
            float w2 = c2 - c1;
            float w3 = wv[t] - c2;
            acc[0].x += w0 * sp[t].x; acc[0].y += w0 * sp[t].y; acc[0].z += w0 * sp[t].z; acc[0].w += w0 * sp[t].w;
            acc[1].x += w1 * sp[t].x; acc[1].y += w1 * sp[t].y; acc[1].z += w1 * sp[t].z; acc[1].w += w1 * sp[t].w;
            acc[2].x += w2 * sp[t].x; acc[2].y += w2 * sp[t].y; acc[2].z += w2 * sp[t].z; acc[2].w += w2 * sp[t].w;
            acc[3].x += w3 * sp[t].x; acc[3].y += w3 * sp[t].y; acc[3].z += w3 * sp[t].z; acc[3].w += w3 * sp[t].w;
        }
    }
}

// ---------- MFMA GEMM (layer 1): A direct from global, B read from LDS ----------
template <int K, int M, bool DYNIN>
__global__ __launch_bounds__(256, 4) void mgemm_kernel(const void* __restrict__ hv_,
                                                       const void* __restrict__ W,
                                                       unsigned short* __restrict__ out,
                                                       const int* __restrict__ flagp) {
    constexpr int KP = K + 8;
    constexpr int NC = M / 16;
    constexpr int NK = K / 32;
    constexpr int NT = (N_NODES + 63) / 64;

    __shared__ unsigned short wt[M][KP];  // W transposed

    const int bf = *flagp;
    const int tid = threadIdx.x;

    for (int i = tid; i < K * M; i += 256) {
        int k = i / M, m = i % M;
        wt[m][k] = f2bf(ldf(W, i, bf));
    }
    __syncthreads();

    const int lane = tid & 63;
    const int qd = lane >> 4;
    const int ln = lane & 15;
    const int wrow = (tid >> 6) * 16;

    for (int tile = blockIdx.x; tile < NT; tile += gridDim.x) {
        const int row = tile * 64 + wrow + ln;
        const bool ok = row < N_NODES;

        f32x4 acc[NC];
#pragma unroll
        for (int c = 0; c < NC; ++c) acc[c] = (f32x4){0.f, 0.f, 0.f, 0.f};

#pragma unroll
        for (int ks = 0; ks < NK; ++ks) {
            bf16x8 a;
            if (ok) {
                const size_t base = (size_t)row * K + ks * 32 + qd * 8;
                if (DYNIN && !bf) {
                    const float* xp = (const float*)hv_ + base;
                    float4 f0 = *(const float4*)xp;
                    float4 f1 = *(const float4*)(xp + 4);
                    ushort4 uu[2];
                    uu[0].x = f2bf(f0.x); uu[0].y = f2bf(f0.y); uu[0].z = f2bf(f0.z); uu[0].w = f2bf(f0.w);
                    uu[1].x = f2bf(f1.x); uu[1].y = f2bf(f1.y); uu[1].z = f2bf(f1.z); uu[1].w = f2bf(f1.w);
                    a = *(const bf16x8*)uu;
                } else {
                    a = *(const bf16x8*)((const unsigned short*)hv_ + base);
                }
            } else {
                a = (bf16x8)(__bf16)0.0f;
            }
#pragma unroll
            for (int c = 0; c < NC; ++c) {
                bf16x8 b = *(const bf16x8*)&wt[c * 16 + ln][ks * 32 + qd * 8];
                acc[c] = __builtin_amdgcn_mfma_f32_16x16x32_bf16(a, b, acc[c], 0, 0, 0);
            }
        }

#pragma unroll
        for (int c = 0; c < NC; ++c) {
#pragma unroll
            for (int r = 0; r < 4; ++r) {
                int orow = tile * 64 + wrow + qd * 4 + r;
                if (orow < N_NODES) out[(size_t)orow * M + c * 16 + ln] = f2bf(acc[c][r]);
            }
        }
    }
}

// ---------- Fused: agg = relu(spmm(support)+bias); out = agg @ W  (K=64 fixed) ----------
// NOTE: no min-waves hint — gather batches need ~90+ live VGPRs to stay in flight.
template <int MOUT>
__global__ __launch_bounds__(256) void fused_kernel(const unsigned short* __restrict__ support,
                                                    const int* __restrict__ row_start,
                                                    const int2* __restrict__ csr_rec,
                                                    const void* __restrict__ bias,
                                                    const void* __restrict__ W,
                                                    unsigned short* __restrict__ out,
                                                    const int* __restrict__ flagp) {
    constexpr int K = 64, KP = 72;
    constexpr int NC = MOUT / 16;
    constexpr int NK = 2;
    constexpr int NT = (N_NODES + 63) / 64;

    __shared__ unsigned short agg[64][KP];
    __shared__ unsigned short wt[MOUT][KP];

    const int bf = *flagp;
    const int tid = threadIdx.x;

    for (int i = tid; i < K * MOUT; i += 256) {
        int k = i / MOUT, m = i % MOUT;
        wt[m][k] = f2bf(ldf(W, i, bf));
    }
    __syncthreads();

    const int lane = tid & 63;
    const int qd = lane >> 4;
    const int ln = lane & 15;
    const int wrow = (tid >> 6) * 16;

    // gather mapping: group g = tid>>4 handles rows g*4..g*4+3; lane c = tid&15 -> cols c*4..+3
    const int grp = tid >> 4;
    const int cc = tid & 15;
    const float4 bias4 = make_float4(ldf(bias, cc * 4 + 0, bf), ldf(bias, cc * 4 + 1, bf),
                                     ldf(bias, cc * 4 + 2, bf), ldf(bias, cc * 4 + 3, bf));
    const unsigned short* supc = support + cc * 4;

    for (int tile = blockIdx.x; tile < NT; tile += gridDim.x) {
        const int r0 = tile * 64 + grp * 4;
        int s  = row_start[min(r0 + 0, N_NODES)];
        int b1 = row_start[min(r0 + 1, N_NODES)];
        int b2 = row_start[min(r0 + 2, N_NODES)];
        int b3 = row_start[min(r0 + 3, N_NODES)];
        int e  = row_start[min(r0 + 4, N_NODES)];

        float4 acc[4] = {bias4, bias4, bias4, bias4};
        quad_gather<64>(supc, csr_rec, s, b1, b2, b3, e, acc);
#pragma unroll
        for (int k = 0; k < 4; ++k) {
            float4 a = acc[k];
            a.x = fmaxf(a.x, 0.f); a.y = fmaxf(a.y, 0.f);
            a.z = fmaxf(a.z, 0.f); a.w = fmaxf(a.w, 0.f);
            st4_half(&agg[grp * 4 + k][cc * 4], a);
        }
        __syncthreads();

        f32x4 macc[NC];
#pragma unroll
        for (int c = 0; c < NC; ++c) macc[c] = (f32x4){0.f, 0.f, 0.f, 0.f};
#pragma unroll
        for (int ks = 0; ks < NK; ++ks) {
            bf16x8 a = *(const bf16x8*)&agg[wrow + ln][ks * 32 + qd * 8];
#pragma unroll
            for (int c = 0; c < NC; ++c) {
                bf16x8 b = *(const bf16x8*)&wt[c * 16 + ln][ks * 32 + qd * 8];
                macc[c] = __builtin_amdgcn_mfma_f32_16x16x32_bf16(a, b, macc[c], 0, 0, 0);
            }
        }

#pragma unroll
        for (int c = 0; c < NC; ++c) {
#pragma unroll
            for (int r = 0; r < 4; ++r) {
                int orow = tile * 64 + wrow + qd * 4 + r;
                if (orow < N_NODES) out[(size_t)orow * MOUT + c * 16 + ln] = f2bf(macc[c][r]);
            }
        }
        __syncthreads();  // agg reused next tile
    }
}

// ---------- final SpMM (M=16): flat quad-row gather, 4 lanes per row ----------
template <bool DYNOUT>
__global__ __launch_bounds__(256) void spmm16_kernel(const unsigned short* __restrict__ support,
                                                     const int* __restrict__ row_start,
                                                     const int2* __restrict__ csr_rec,
                                                     const void* __restrict__ bias,
                                                     void* __restrict__ out_,
                                                     const int* __restrict__ flagp) {
    constexpr int M = 16;
    int bf = *flagp;
    int tid = threadIdx.x;
    int grp = tid >> 2;           // 64 groups x 4 rows = 256 rows per block
    int cc = tid & 3;             // 4 lanes x 4 cols
    int r0 = blockIdx.x * 256 + grp * 4;
    if (r0 >= N_NODES) return;
    int s  = row_start[min(r0 + 0, N_NODES)];
    int b1 = row_start[min(r0 + 1, N_NODES)];
    int b2 = row_start[min(r0 + 2, N_NODES)];
    int b3 = row_start[min(r0 + 3, N_NODES)];
    int e  = row_start[min(r0 + 4, N_NODES)];
    float4 bias4 = make_float4(ldf(bias, cc * 4 + 0, bf), ldf(bias, cc * 4 + 1, bf),
                               ldf(bias, cc * 4 + 2, bf), ldf(bias, cc * 4 + 3, bf));
    float4 acc[4] = {bias4, bias4, bias4, bias4};
    quad_gather<16>(support + cc * 4, csr_rec, s, b1, b2, b3, e, acc);
#pragma unroll
    for (int k = 0; k < 4; ++k) {
        int row = r0 + k;
        if (row < N_NODES) {
            if (DYNOUT && !bf) *(float4*)((float*)out_ + (size_t)row * M + cc * 4) = acc[k];
            else               st4_half((unsigned short*)out_ + (size_t)row * M + cc * 4, acc[k]);
        }
    }
}

extern "C" void kernel_launch(void* const* d_in, const int* in_sizes, int n_in,
                              void* d_out, int out_size, void* d_ws, size_t ws_size,
                              hipStream_t stream) {
    (void)in_sizes; (void)n_in; (void)out_size; (void)ws_size;
    const void* x  = d_in[0];
    const void* ev = d_in[1];
    const void* W1 = d_in[2];
    const void* b1 = d_in[3];
    const void* W2 = d_in[4];
    const void* b2 = d_in[5];
    const void* W3 = d_in[6];
    const void* b3 = d_in[7];
    const int* esrc = (const int*)d_in[8];
    const int* edst = (const int*)d_in[9];

    // workspace (~34 MB)
    char* ws = (char*)d_ws;
    size_t off = 0;
    auto alloc = [&](size_t bytes) -> void* {
        void* p = ws + off;
        off = (off + bytes + 255) & ~(size_t)255;
        return p;
    };
    unsigned short* A = (unsigned short*)alloc((size_t)N_NODES * 64 * 2);  // support1 / A3
    unsigned short* B = (unsigned short*)alloc((size_t)N_NODES * 64 * 2);  // A2
    int* row_start  = (int*)alloc((size_t)(N_NODES + 1) * 4);
    int* bcount     = (int*)alloc(512);
    int* bstart     = (int*)alloc(512);
    int* bcursor    = (int*)alloc(512);
    int2* csr_rec   = (int2*)alloc((size_t)N_EDGES * 8);
    int* flagp      = (int*)alloc(256);
    // part[] (8 MB) aliases A (12.8 MB): dead before mgemm1 writes A
    int2* part      = (int2*)A;

    // ---- dtype probe ----
    detect_kernel<<<1, 256, 0, stream>>>((const unsigned short*)x, flagp);

    // ---- bucket-local CSR build ----
    hipMemsetAsync(bcount, 0, 512, stream);
    bhist_kernel<<<(N_EDGES + 4095) / 4096, 256, 0, stream>>>(edst, bcount);
    bscan_kernel<<<1, 128, 0, stream>>>(bcount, bstart, bcursor);
    part_kernel<<<(N_EDGES + 2047) / 2048, 256, 0, stream>>>(esrc, edst, ev, bcursor, part, flagp);
    place_kernel<<<NBUCK, 512, 0, stream>>>(bstart, part, row_start, csr_rec);

    // ---- layer 1: A = x @ W1 ----
    mgemm_kernel<128, 64, true><<<1024, 256, 0, stream>>>(x, W1, A, flagp);
    // ---- layer 1 agg + layer 2 gemm fused: B = relu(spmm(A)+b1) @ W2 ----
    fused_kernel<64><<<1024, 256, 0, stream>>>(A, row_start, csr_rec, b1, W2, B, flagp);
    // ---- layer 2 agg + layer 3 gemm fused: A(=A3) = relu(spmm(B)+b2) @ W3 ----
    fused_kernel<16><<<1024, 256, 0, stream>>>(B, row_start, csr_rec, b2, W3, A, flagp);
    // ---- final aggregation: out = spmm(A3) + b3 ----
    spmm16_kernel<true><<<(N_NODES + 255) / 256, 256, 0, stream>>>(A, row_start, csr_rec, b3, d_out, flagp);
}